// Round 1
// baseline (3689.022 us; speedup 1.0000x reference)
//
#include <hip/hip_runtime.h>
#include <math.h>

#define HID 128
#define NEXP 8
#define NGRAPH 64

// ---------------- init: deg = 1 (self loop), pool sums/counts = 0 -------------
__global__ void k_init(float* deg, float* pool, int n) {
    int i = blockIdx.x * blockDim.x + threadIdx.x;
    if (i < n) deg[i] = 1.0f;
    if (i < NGRAPH * NEXP + NGRAPH) pool[i] = 0.0f;
}

// ---------------- degree scatter ----------------------------------------------
__global__ void k_deg(const int* __restrict__ dst, float* __restrict__ deg, int e) {
    int i = blockIdx.x * blockDim.x + threadIdx.x;
    if (i < e) atomicAdd(&deg[dst[i]], 1.0f);
}

__global__ void k_dinv(const float* __restrict__ deg, float* __restrict__ dinv, int n) {
    int i = blockIdx.x * blockDim.x + threadIdx.x;
    if (i < n) dinv[i] = rsqrtf(deg[i]);
}

// ---------------- layer 1 dense: h1 = x@W1, hs1 = h1*dinv, agg init = hs1 -----
__global__ void k_h1(const float* __restrict__ an, const float* __restrict__ pos,
                     const float* __restrict__ W1, const float* __restrict__ dinv,
                     float* __restrict__ hs1, float* __restrict__ agg1, long n) {
    long idx = (long)blockIdx.x * blockDim.x + threadIdx.x;
    if (idx >= n * HID) return;
    int i = (int)(idx >> 7);
    int j = (int)(idx & 127);
    float x0 = an[i];
    float x1 = pos[3 * i + 0];
    float x2 = pos[3 * i + 1];
    float x3 = pos[3 * i + 2];
    float h = x0 * W1[0 * HID + j] + x1 * W1[1 * HID + j] +
              x2 * W1[2 * HID + j] + x3 * W1[3 * HID + j];
    float hs = h * dinv[i];
    hs1[idx]  = hs;
    agg1[idx] = hs;   // self-loop term: out = dinv[i]*(sum_src hs[src] + hs[i]) + b
}

// ---------------- edge scatter: agg[dst] += hs[src], one block per edge -------
__global__ void k_scatter(const int* __restrict__ src, const int* __restrict__ dst,
                          const float* __restrict__ hs, float* __restrict__ agg, int e) {
    int eid = blockIdx.x;
    if (eid >= e) return;
    int c = threadIdx.x;
    long s = src[eid];
    long d = dst[eid];
    atomicAdd(&agg[d * HID + c], hs[s * HID + c]);
}

// ---------------- x1 = relu(dinv*agg1 + b1), in place -------------------------
__global__ void k_x1(float* __restrict__ agg1, const float* __restrict__ b1,
                     const float* __restrict__ dinv, long n) {
    long idx = (long)blockIdx.x * blockDim.x + threadIdx.x;
    if (idx >= n * HID) return;
    int i = (int)(idx >> 7);
    int j = (int)(idx & 127);
    float v = dinv[i] * agg1[idx] + b1[j];
    agg1[idx] = v > 0.0f ? v : 0.0f;
}

// ---------------- layer 2 dense: hs2 = (x1@W2)*dinv, agg2 init = hs2 ----------
__global__ void k_h2(const float* __restrict__ x1, const float* __restrict__ W2,
                     const float* __restrict__ dinv, float* __restrict__ hs2,
                     float* __restrict__ agg2, int n) {
    __shared__ float xs[HID];
    int i = blockIdx.x;
    if (i >= n) return;
    int j = threadIdx.x;
    xs[j] = x1[(long)i * HID + j];
    __syncthreads();
    float acc = 0.0f;
#pragma unroll 8
    for (int k = 0; k < HID; k++) acc += xs[k] * W2[k * HID + j];
    float hs = acc * dinv[i];
    hs2[(long)i * HID + j]  = hs;
    agg2[(long)i * HID + j] = hs;
}

// ---------------- per-node projection + graph pooling -------------------------
// one wave (64 threads) per node: x2[j] = dinv*agg2[j]+b2[j]; logits = x2@Wlin;
// wave-reduce; lane0 atomically accumulates into pool sums + counts.
__global__ void k_pool(const float* __restrict__ agg2, const float* __restrict__ b2,
                       const float* __restrict__ dinv, const float* __restrict__ Wlin,
                       const float* __restrict__ blin, const int* __restrict__ batch,
                       float* __restrict__ pool, int n) {
    int i = blockIdx.x;
    if (i >= n) return;
    int t = threadIdx.x;   // 0..63
    float di = dinv[i];
    float xa = di * agg2[(long)i * HID + t]      + b2[t];
    float xb = di * agg2[(long)i * HID + 64 + t] + b2[64 + t];
    float p[NEXP];
#pragma unroll
    for (int k = 0; k < NEXP; k++)
        p[k] = xa * Wlin[t * NEXP + k] + xb * Wlin[(t + 64) * NEXP + k];
#pragma unroll
    for (int off = 32; off > 0; off >>= 1) {
#pragma unroll
        for (int k = 0; k < NEXP; k++)
            p[k] += __shfl_down(p[k], off, 64);
    }
    if (t == 0) {
        int g = batch[i];
#pragma unroll
        for (int k = 0; k < NEXP; k++)
            atomicAdd(&pool[g * NEXP + k], p[k] + blin[k]);
        atomicAdd(&pool[NGRAPH * NEXP + g], 1.0f);
    }
}

// ---------------- mean + log_softmax ------------------------------------------
__global__ void k_lsm(const float* __restrict__ pool, float* __restrict__ out) {
    int g = threadIdx.x;   // 0..63
    if (g >= NGRAPH) return;
    float cnt = fmaxf(pool[NGRAPH * NEXP + g], 1.0f);
    float v[NEXP];
    float m = -1e30f;
#pragma unroll
    for (int k = 0; k < NEXP; k++) {
        v[k] = pool[g * NEXP + k] / cnt;
        m = fmaxf(m, v[k]);
    }
    float s = 0.0f;
#pragma unroll
    for (int k = 0; k < NEXP; k++) s += expf(v[k] - m);
    float ls = logf(s);
#pragma unroll
    for (int k = 0; k < NEXP; k++) out[g * NEXP + k] = v[k] - m - ls;
}

extern "C" void kernel_launch(void* const* d_in, const int* in_sizes, int n_in,
                              void* d_out, int out_size, void* d_ws, size_t ws_size,
                              hipStream_t stream) {
    const float* an   = (const float*)d_in[0];
    const float* pos  = (const float*)d_in[1];
    const int*   ei   = (const int*)d_in[2];     // [2, E] flat
    const int*   batch= (const int*)d_in[3];
    const float* W1   = (const float*)d_in[4];
    const float* b1   = (const float*)d_in[5];
    const float* W2   = (const float*)d_in[6];
    const float* b2   = (const float*)d_in[7];
    const float* Wlin = (const float*)d_in[8];
    const float* blin = (const float*)d_in[9];
    float* out = (float*)d_out;

    const int n = in_sizes[0];
    const int e = in_sizes[2] / 2;
    const int* src = ei;
    const int* dst = ei + e;

    // workspace layout (floats)
    float* ws   = (float*)d_ws;
    float* deg  = ws;                       // n
    float* dinv = ws + n;                   // n
    float* pool = ws + 2L * n;              // 64*8 + 64
    float* bufA = pool + (NGRAPH * NEXP + NGRAPH);   // n*HID  (hs1, then agg2)
    float* bufB = bufA + (long)n * HID;              // n*HID  (agg1 -> x1)
    float* bufC = bufB + (long)n * HID;              // n*HID  (hs2)

    const int nhBlocks = (int)(((long)n * HID + 255) / 256);

    k_init<<<(n + 255) / 256, 256, 0, stream>>>(deg, pool, n);
    k_deg<<<(e + 255) / 256, 256, 0, stream>>>(dst, deg, e);
    k_dinv<<<(n + 255) / 256, 256, 0, stream>>>(deg, dinv, n);

    // layer 1
    k_h1<<<nhBlocks, 256, 0, stream>>>(an, pos, W1, dinv, bufA, bufB, n);
    k_scatter<<<e, HID, 0, stream>>>(src, dst, bufA, bufB, e);
    k_x1<<<nhBlocks, 256, 0, stream>>>(bufB, b1, dinv, n);

    // layer 2
    k_h2<<<n, HID, 0, stream>>>(bufB, W2, dinv, bufC, bufA, n);
    k_scatter<<<e, HID, 0, stream>>>(src, dst, bufC, bufA, e);

    // projection + pooling + log_softmax
    k_pool<<<n, 64, 0, stream>>>(bufA, b2, dinv, Wlin, blin, batch, pool, n);
    k_lsm<<<1, 64, 0, stream>>>(pool, out);
}

// Round 2
// 899.745 us; speedup vs baseline: 4.1001x; 4.1001x over previous
//
#include <hip/hip_runtime.h>
#include <math.h>

#define HID 128
#define NEXP 8
#define NGRAPH 64

// ---------------- init: cnt = 0 (int), pool = 0 -------------------------------
__global__ void k_init(int* __restrict__ cnt, float* __restrict__ pool, int n) {
    int i = blockIdx.x * blockDim.x + threadIdx.x;
    if (i < n) cnt[i] = 0;
    if (i < NGRAPH * NEXP + NGRAPH) pool[i] = 0.0f;
}

// ---------------- per-dst edge histogram --------------------------------------
__global__ void k_cnt(const int* __restrict__ dst, int* __restrict__ cnt, int e) {
    int i = blockIdx.x * blockDim.x + threadIdx.x;
    if (i < e) atomicAdd(&cnt[dst[i]], 1);
}

// ---------------- dinv = rsqrt(cnt + 1)  (the +1 is the self-loop) ------------
__global__ void k_dinv(const int* __restrict__ cnt, float* __restrict__ dinv, int n) {
    int i = blockIdx.x * blockDim.x + threadIdx.x;
    if (i < n) dinv[i] = rsqrtf((float)cnt[i] + 1.0f);
}

// ---------------- exclusive scan, 2-level -------------------------------------
__global__ void k_scan_block(const int* __restrict__ cnt, int* __restrict__ off,
                             int* __restrict__ bsum, int n) {
    __shared__ int s[256];
    int t = threadIdx.x;
    int i = blockIdx.x * 256 + t;
    int v = (i < n) ? cnt[i] : 0;
    s[t] = v;
    __syncthreads();
    for (int d = 1; d < 256; d <<= 1) {
        int x = (t >= d) ? s[t - d] : 0;
        __syncthreads();
        s[t] += x;
        __syncthreads();
    }
    if (i < n) off[i] = s[t] - v;           // exclusive
    if (t == 255) bsum[blockIdx.x] = s[255];
}

__global__ void k_scan_top(int* __restrict__ bsum, int nb) {
    __shared__ int s[512];
    int t = threadIdx.x;
    int v = (t < nb) ? bsum[t] : 0;
    s[t] = v;
    __syncthreads();
    for (int d = 1; d < 512; d <<= 1) {
        int x = (t >= d) ? s[t - d] : 0;
        __syncthreads();
        s[t] += x;
        __syncthreads();
    }
    if (t < nb) bsum[t] = s[t] - v;         // exclusive
}

__global__ void k_add_off(int* __restrict__ off, const int* __restrict__ bsum,
                          int* __restrict__ cur, int n) {
    int i = blockIdx.x * 256 + threadIdx.x;
    if (i < n) {
        int o = off[i] + bsum[blockIdx.x];
        off[i] = o;
        cur[i] = o;
    }
}

// ---------------- CSR fill: bucket src ids by dst ------------------------------
__global__ void k_fill(const int* __restrict__ src, const int* __restrict__ dst,
                       int* __restrict__ cur, int* __restrict__ eidx, int e) {
    int i = blockIdx.x * blockDim.x + threadIdx.x;
    if (i < e) {
        int p = atomicAdd(&cur[dst[i]], 1);
        eidx[p] = src[i];
    }
}

// ---------------- layer 1 dense: hs1 = (x@W1)*dinv ----------------------------
__global__ void k_h1(const float* __restrict__ an, const float* __restrict__ pos,
                     const float* __restrict__ W1, const float* __restrict__ dinv,
                     float* __restrict__ hs1, long n) {
    long idx = (long)blockIdx.x * blockDim.x + threadIdx.x;
    if (idx >= n * HID) return;
    int i = (int)(idx >> 7);
    int j = (int)(idx & 127);
    float x0 = an[i];
    float x1 = pos[3 * i + 0];
    float x2 = pos[3 * i + 1];
    float x3 = pos[3 * i + 2];
    float h = x0 * W1[0 * HID + j] + x1 * W1[1 * HID + j] +
              x2 * W1[2 * HID + j] + x3 * W1[3 * HID + j];
    hs1[idx] = h * dinv[i];
}

// ---------------- gather: out[i] = act(dinv[i]*(hs[i] + sum_src hs[src]) + b) --
// one wave per dst node; 4 waves per 256-thread block.
__global__ void k_gather(const float* __restrict__ hs, const int* __restrict__ eidx,
                         const int* __restrict__ off, const int* __restrict__ cnt,
                         const float* __restrict__ dinv, const float* __restrict__ b,
                         float* __restrict__ out, int n, int relu) {
    int w = threadIdx.x >> 6;
    int lane = threadIdx.x & 63;
    int i = blockIdx.x * 4 + w;
    if (i >= n) return;
    long row = (long)i * HID;
    float a0 = hs[row + lane];          // self-loop
    float a1 = hs[row + 64 + lane];
    int o = off[i], c = cnt[i];
    for (int k = 0; k < c; k++) {
        long s = (long)eidx[o + k] * HID;
        a0 += hs[s + lane];
        a1 += hs[s + 64 + lane];
    }
    float di = dinv[i];
    float v0 = di * a0 + b[lane];
    float v1 = di * a1 + b[64 + lane];
    if (relu) { v0 = fmaxf(v0, 0.0f); v1 = fmaxf(v1, 0.0f); }
    out[row + lane] = v0;
    out[row + 64 + lane] = v1;
}

// ---------------- layer 2 dense: hs2 = (x1@W2)*dinv ---------------------------
__global__ void k_h2(const float* __restrict__ x1, const float* __restrict__ W2,
                     const float* __restrict__ dinv, float* __restrict__ hs2, int n) {
    __shared__ float xs[HID];
    int i = blockIdx.x;
    if (i >= n) return;
    int j = threadIdx.x;
    xs[j] = x1[(long)i * HID + j];
    __syncthreads();
    float acc = 0.0f;
#pragma unroll 8
    for (int k = 0; k < HID; k++) acc += xs[k] * W2[k * HID + j];
    hs2[(long)i * HID + j] = acc * dinv[i];
}

// ---------------- projection + hierarchical pooling ---------------------------
// 256-thread blocks = 4 waves; each wave handles 32 contiguous nodes; LDS
// accumulation per graph; flush touched graphs once per block.
__global__ void k_pool(const float* __restrict__ x2, const float* __restrict__ Wlin,
                       const int* __restrict__ batch, float* __restrict__ pool, int n) {
    __shared__ float gsum[NGRAPH * NEXP];
    __shared__ float gcnt[NGRAPH];
    __shared__ int touched[NGRAPH];
    int t = threadIdx.x;
    for (int idx = t; idx < NGRAPH * NEXP; idx += 256) gsum[idx] = 0.0f;
    if (t < NGRAPH) { gcnt[t] = 0.0f; touched[t] = 0; }
    __syncthreads();

    int w = t >> 6;
    int lane = t & 63;
    // hoist Wlin rows for this lane into registers
    float wl[NEXP], wh[NEXP];
#pragma unroll
    for (int k = 0; k < NEXP; k++) {
        wl[k] = Wlin[lane * NEXP + k];
        wh[k] = Wlin[(lane + 64) * NEXP + k];
    }
    int base = blockIdx.x * 128 + w * 32;
    for (int q = 0; q < 32; q++) {
        int i = base + q;
        if (i >= n) break;
        long row = (long)i * HID;
        float xa = x2[row + lane];
        float xb = x2[row + 64 + lane];
        float p[NEXP];
#pragma unroll
        for (int k = 0; k < NEXP; k++) p[k] = xa * wl[k] + xb * wh[k];
#pragma unroll
        for (int offd = 32; offd > 0; offd >>= 1) {
#pragma unroll
            for (int k = 0; k < NEXP; k++) p[k] += __shfl_down(p[k], offd, 64);
        }
        if (lane == 0) {
            int g = batch[i];
            touched[g] = 1;
#pragma unroll
            for (int k = 0; k < NEXP; k++) atomicAdd(&gsum[g * NEXP + k], p[k]);
            atomicAdd(&gcnt[g], 1.0f);
        }
    }
    __syncthreads();
    for (int idx = t; idx < NGRAPH * NEXP; idx += 256) {
        int g = idx >> 3;
        if (touched[g]) atomicAdd(&pool[idx], gsum[idx]);
    }
    if (t < NGRAPH && touched[t]) atomicAdd(&pool[NGRAPH * NEXP + t], gcnt[t]);
}

// ---------------- mean + blin + log_softmax -----------------------------------
__global__ void k_lsm(const float* __restrict__ pool, const float* __restrict__ blin,
                      float* __restrict__ out) {
    int g = threadIdx.x;
    if (g >= NGRAPH) return;
    float cnt = fmaxf(pool[NGRAPH * NEXP + g], 1.0f);
    float v[NEXP];
    float m = -1e30f;
#pragma unroll
    for (int k = 0; k < NEXP; k++) {
        v[k] = pool[g * NEXP + k] / cnt + blin[k];
        m = fmaxf(m, v[k]);
    }
    float s = 0.0f;
#pragma unroll
    for (int k = 0; k < NEXP; k++) s += expf(v[k] - m);
    float ls = logf(s);
#pragma unroll
    for (int k = 0; k < NEXP; k++) out[g * NEXP + k] = v[k] - m - ls;
}

extern "C" void kernel_launch(void* const* d_in, const int* in_sizes, int n_in,
                              void* d_out, int out_size, void* d_ws, size_t ws_size,
                              hipStream_t stream) {
    const float* an   = (const float*)d_in[0];
    const float* pos  = (const float*)d_in[1];
    const int*   ei   = (const int*)d_in[2];     // [2, E] flat
    const int*   batch= (const int*)d_in[3];
    const float* W1   = (const float*)d_in[4];
    const float* b1   = (const float*)d_in[5];
    const float* W2   = (const float*)d_in[6];
    const float* b2   = (const float*)d_in[7];
    const float* Wlin = (const float*)d_in[8];
    const float* blin = (const float*)d_in[9];
    float* out = (float*)d_out;

    const int n = in_sizes[0];
    const int e = in_sizes[2] / 2;
    const int* src = ei;
    const int* dst = ei + e;

    // workspace layout
    char* p = (char*)d_ws;
    int*   cnt  = (int*)p;            p += sizeof(int) * (size_t)n;
    int*   off  = (int*)p;            p += sizeof(int) * (size_t)n;
    int*   cur  = (int*)p;            p += sizeof(int) * (size_t)n;
    int*   eidx = (int*)p;            p += sizeof(int) * (size_t)e;
    int*   bsum = (int*)p;            p += sizeof(int) * 512;
    float* dinv = (float*)p;          p += sizeof(float) * (size_t)n;
    float* pool = (float*)p;          p += sizeof(float) * (NGRAPH * NEXP + NGRAPH);
    float* bufA = (float*)p;          p += sizeof(float) * (size_t)n * HID;
    float* bufB = (float*)p;          p += sizeof(float) * (size_t)n * HID;

    const int nb256 = (n + 255) / 256;
    const int nhBlocks = (int)(((long)n * HID + 255) / 256);

    // CSR build
    k_init<<<nb256, 256, 0, stream>>>(cnt, pool, n);
    k_cnt<<<(e + 255) / 256, 256, 0, stream>>>(dst, cnt, e);
    k_dinv<<<nb256, 256, 0, stream>>>(cnt, dinv, n);
    k_scan_block<<<nb256, 256, 0, stream>>>(cnt, off, bsum, n);
    k_scan_top<<<1, 512, 0, stream>>>(bsum, nb256);
    k_add_off<<<nb256, 256, 0, stream>>>(off, bsum, cur, n);
    k_fill<<<(e + 255) / 256, 256, 0, stream>>>(src, dst, cur, eidx, e);

    // layer 1
    k_h1<<<nhBlocks, 256, 0, stream>>>(an, pos, W1, dinv, bufA, n);
    k_gather<<<(n + 3) / 4, 256, 0, stream>>>(bufA, eidx, off, cnt, dinv, b1, bufB, n, 1);

    // layer 2
    k_h2<<<n, HID, 0, stream>>>(bufB, W2, dinv, bufA, n);
    k_gather<<<(n + 3) / 4, 256, 0, stream>>>(bufA, eidx, off, cnt, dinv, b2, bufB, n, 0);

    // projection + pooling + log_softmax
    k_pool<<<(n + 127) / 128, 256, 0, stream>>>(bufB, Wlin, batch, pool, n);
    k_lsm<<<1, 64, 0, stream>>>(pool, blin, out);
}

// Round 3
// 540.237 us; speedup vs baseline: 6.8285x; 1.6655x over previous
//
#include <hip/hip_runtime.h>
#include <math.h>

#define HID 128
#define NEXP 8
#define NGRAPH 64

typedef __attribute__((ext_vector_type(8))) short short8;
typedef __attribute__((ext_vector_type(4))) float float4v;

__device__ inline unsigned short f2bf(float f) {
    unsigned u = __float_as_uint(f);
    u += 0x7FFF + ((u >> 16) & 1);          // RNE
    return (unsigned short)(u >> 16);
}
__device__ inline unsigned packbf(float lo, float hi) {
    return (unsigned)f2bf(lo) | ((unsigned)f2bf(hi) << 16);
}
__device__ inline float bflo(unsigned u) { return __uint_as_float(u << 16); }
__device__ inline float bfhi(unsigned u) { return __uint_as_float(u & 0xFFFF0000u); }

// ---------------- init: cnt = 0 (int), pool = 0 -------------------------------
__global__ void k_init(int* __restrict__ cnt, float* __restrict__ pool, int n) {
    int i = blockIdx.x * blockDim.x + threadIdx.x;
    if (i < n) cnt[i] = 0;
    if (i < NGRAPH * NEXP + NGRAPH) pool[i] = 0.0f;
}

// ---------------- per-dst edge histogram --------------------------------------
__global__ void k_cnt(const int* __restrict__ dst, int* __restrict__ cnt, int e) {
    int i = blockIdx.x * blockDim.x + threadIdx.x;
    if (i < e) atomicAdd(&cnt[dst[i]], 1);
}

// ---------------- exclusive scan (block level) + fused dinv -------------------
__global__ void k_scan_block(const int* __restrict__ cnt, int* __restrict__ off,
                             int* __restrict__ bsum, float* __restrict__ dinv, int n) {
    __shared__ int s[256];
    int t = threadIdx.x;
    int i = blockIdx.x * 256 + t;
    int v = (i < n) ? cnt[i] : 0;
    if (i < n) dinv[i] = rsqrtf((float)v + 1.0f);   // +1 = self-loop
    s[t] = v;
    __syncthreads();
    for (int d = 1; d < 256; d <<= 1) {
        int x = (t >= d) ? s[t - d] : 0;
        __syncthreads();
        s[t] += x;
        __syncthreads();
    }
    if (i < n) off[i] = s[t] - v;           // exclusive
    if (t == 255) bsum[blockIdx.x] = s[255];
}

__global__ void k_scan_top(int* __restrict__ bsum, int nb) {
    __shared__ int s[512];
    int t = threadIdx.x;
    int v = (t < nb) ? bsum[t] : 0;
    s[t] = v;
    __syncthreads();
    for (int d = 1; d < 512; d <<= 1) {
        int x = (t >= d) ? s[t - d] : 0;
        __syncthreads();
        s[t] += x;
        __syncthreads();
    }
    if (t < nb) bsum[t] = s[t] - v;         // exclusive
}

__global__ void k_add_off(int* __restrict__ off, const int* __restrict__ bsum,
                          int* __restrict__ cur, int n) {
    int i = blockIdx.x * 256 + threadIdx.x;
    if (i < n) {
        int o = off[i] + bsum[blockIdx.x];
        off[i] = o;
        cur[i] = o;
    }
}

// ---------------- CSR fill: bucket src ids by dst ------------------------------
__global__ void k_fill(const int* __restrict__ src, const int* __restrict__ dst,
                       int* __restrict__ cur, int* __restrict__ eidx, int e) {
    int i = blockIdx.x * blockDim.x + threadIdx.x;
    if (i < e) {
        int p = atomicAdd(&cur[dst[i]], 1);
        eidx[p] = src[i];
    }
}

// ---------------- W2 (fp32 [k][n]) -> W2t (bf16 [n][k]) ------------------------
__global__ void k_w2t(const float* __restrict__ W2, unsigned short* __restrict__ W2t) {
    int id = blockIdx.x * blockDim.x + threadIdx.x;   // 0..16383
    if (id >= HID * HID) return;
    int k = id >> 7, nn = id & 127;
    W2t[nn * HID + k] = f2bf(W2[id]);
}

// ---------------- layer 1 dense: hs1 = (x@W1)*dinv, bf16 out -------------------
// one wave per node; lane p covers cols 2p, 2p+1
__global__ void k_h1(const float* __restrict__ an, const float* __restrict__ pos,
                     const float* __restrict__ W1, const float* __restrict__ dinv,
                     unsigned* __restrict__ hs1, int n) {
    int i = blockIdx.x * 4 + (threadIdx.x >> 6);
    if (i >= n) return;
    int p = threadIdx.x & 63;
    const float2* W1v = (const float2*)W1;
    float2 w0 = W1v[0 * 64 + p], w1 = W1v[1 * 64 + p],
           w2 = W1v[2 * 64 + p], w3 = W1v[3 * 64 + p];
    float x0 = an[i], px = pos[3 * i], py = pos[3 * i + 1], pz = pos[3 * i + 2];
    float di = dinv[i];
    float h0 = (x0 * w0.x + px * w1.x + py * w2.x + pz * w3.x) * di;
    float h1 = (x0 * w0.y + px * w1.y + py * w2.y + pz * w3.y) * di;
    hs1[(size_t)i * 64 + p] = packbf(h0, h1);
}

// ---------------- gather: out[i] = act(dinv[i]*(hs[i] + sum_src hs[src]) + b) --
// one wave per dst node; bf16 rows: 1 dword load per lane covers the whole row.
__global__ void k_gather(const unsigned* __restrict__ hs, const int* __restrict__ eidx,
                         const int* __restrict__ off, const int* __restrict__ cnt,
                         const float* __restrict__ dinv, const float* __restrict__ b,
                         unsigned* __restrict__ out, int n, int relu) {
    int w = threadIdx.x >> 6;
    int lane = threadIdx.x & 63;
    int i = blockIdx.x * 4 + w;
    if (i >= n) return;
    unsigned u = hs[(size_t)i * 64 + lane];       // self-loop
    float a0 = bflo(u), a1 = bfhi(u);
    int o = off[i], c = cnt[i];
    int k = 0;
    for (; k + 4 <= c; k += 4) {
        int s0 = eidx[o + k], s1 = eidx[o + k + 1];
        int s2 = eidx[o + k + 2], s3 = eidx[o + k + 3];
        unsigned u0 = hs[(size_t)s0 * 64 + lane];
        unsigned u1 = hs[(size_t)s1 * 64 + lane];
        unsigned u2 = hs[(size_t)s2 * 64 + lane];
        unsigned u3 = hs[(size_t)s3 * 64 + lane];
        a0 += bflo(u0) + bflo(u1) + bflo(u2) + bflo(u3);
        a1 += bfhi(u0) + bfhi(u1) + bfhi(u2) + bfhi(u3);
    }
    for (; k < c; k++) {
        unsigned uu = hs[(size_t)eidx[o + k] * 64 + lane];
        a0 += bflo(uu);
        a1 += bfhi(uu);
    }
    float2 bb = ((const float2*)b)[lane];
    float di = dinv[i];
    float v0 = di * a0 + bb.x;
    float v1 = di * a1 + bb.y;
    if (relu) { v0 = fmaxf(v0, 0.0f); v1 = fmaxf(v1, 0.0f); }
    out[(size_t)i * 64 + lane] = packbf(v0, v1);
}

// ---------------- layer 2: hs2 = (x1@W2)*dinv via MFMA bf16 --------------------
// block = 256 threads = 4 waves; block covers 64 rows (16/wave); W2t in LDS.
#define W2PAD 136   // 128 + 8 shorts: 16B-aligned rows, 2-way-only bank conflicts
__global__ void __launch_bounds__(256) k_h2(
        const unsigned short* __restrict__ x1, const unsigned short* __restrict__ W2t,
        const float* __restrict__ dinv, unsigned short* __restrict__ hs2, int n) {
    __shared__ short w2s[HID * W2PAD];
    int t = threadIdx.x;
    // stage W2t (bf16 [n][k]) into LDS with padded rows, 16B chunks
    for (int it = 0; it < 8; it++) {
        int c8 = it * 256 + t;               // 0..2047
        int row = c8 >> 4, ch = c8 & 15;
        *(short8*)&w2s[row * W2PAD + ch * 8] = ((const short8*)W2t)[row * 16 + ch];
    }
    __syncthreads();

    int w = t >> 6, l = t & 63;
    int lm = l & 15, lq = l >> 4;
    int base = blockIdx.x * 64 + w * 16;
    int arow = base + lm;
    int arow_c = arow < n ? arow : n - 1;
    const short8* xrow = (const short8*)(x1 + (size_t)arow_c * HID);
    short8 a0 = xrow[lq + 0], a1 = xrow[lq + 4], a2 = xrow[lq + 8], a3 = xrow[lq + 12];

    float4v acc[8];
#pragma unroll
    for (int nt = 0; nt < 8; nt++) acc[nt] = (float4v){0.f, 0.f, 0.f, 0.f};

#pragma unroll
    for (int nt = 0; nt < 8; nt++) {
        const short* bp = &w2s[(nt * 16 + lm) * W2PAD + lq * 8];
        short8 b0 = *(const short8*)(bp);
        short8 b1 = *(const short8*)(bp + 32);
        short8 b2 = *(const short8*)(bp + 64);
        short8 b3 = *(const short8*)(bp + 96);
        acc[nt] = __builtin_amdgcn_mfma_f32_16x16x32_bf16(a0, b0, acc[nt], 0, 0, 0);
        acc[nt] = __builtin_amdgcn_mfma_f32_16x16x32_bf16(a1, b1, acc[nt], 0, 0, 0);
        acc[nt] = __builtin_amdgcn_mfma_f32_16x16x32_bf16(a2, b2, acc[nt], 0, 0, 0);
        acc[nt] = __builtin_amdgcn_mfma_f32_16x16x32_bf16(a3, b3, acc[nt], 0, 0, 0);
    }

    // epilogue: C row = base + lq*4 + r, col = nt*16 + lm
    float di[4];
    int orow[4];
#pragma unroll
    for (int r = 0; r < 4; r++) {
        orow[r] = base + lq * 4 + r;
        di[r] = dinv[orow[r] < n ? orow[r] : n - 1];
    }
#pragma unroll
    for (int nt = 0; nt < 8; nt++) {
#pragma unroll
        for (int r = 0; r < 4; r++) {
            if (orow[r] < n)
                hs2[(size_t)orow[r] * HID + nt * 16 + lm] = f2bf(acc[nt][r] * di[r]);
        }
    }
}

// ---------------- projection + hierarchical pooling (bf16 in) ------------------
__global__ void k_pool(const unsigned* __restrict__ x2, const float* __restrict__ Wlin,
                       const int* __restrict__ batch, float* __restrict__ pool, int n) {
    __shared__ float gsum[NGRAPH * NEXP];
    __shared__ float gcnt[NGRAPH];
    __shared__ int touched[NGRAPH];
    int t = threadIdx.x;
    for (int idx = t; idx < NGRAPH * NEXP; idx += 256) gsum[idx] = 0.0f;
    if (t < NGRAPH) { gcnt[t] = 0.0f; touched[t] = 0; }
    __syncthreads();

    int w = t >> 6;
    int lane = t & 63;
    float wl[NEXP], wh[NEXP];
#pragma unroll
    for (int k = 0; k < NEXP; k++) {
        wl[k] = Wlin[(2 * lane) * NEXP + k];
        wh[k] = Wlin[(2 * lane + 1) * NEXP + k];
    }
    int base = blockIdx.x * 128 + w * 32;
    for (int q = 0; q < 32; q++) {
        int i = base + q;
        if (i >= n) break;
        unsigned u = x2[(size_t)i * 64 + lane];
        float xa = bflo(u), xb = bfhi(u);
        float p[NEXP];
#pragma unroll
        for (int k = 0; k < NEXP; k++) p[k] = xa * wl[k] + xb * wh[k];
#pragma unroll
        for (int offd = 32; offd > 0; offd >>= 1) {
#pragma unroll
            for (int k = 0; k < NEXP; k++) p[k] += __shfl_down(p[k], offd, 64);
        }
        if (lane == 0) {
            int g = batch[i];
            touched[g] = 1;
#pragma unroll
            for (int k = 0; k < NEXP; k++) atomicAdd(&gsum[g * NEXP + k], p[k]);
            atomicAdd(&gcnt[g], 1.0f);
        }
    }
    __syncthreads();
    for (int idx = t; idx < NGRAPH * NEXP; idx += 256) {
        int g = idx >> 3;
        if (touched[g]) atomicAdd(&pool[idx], gsum[idx]);
    }
    if (t < NGRAPH && touched[t]) atomicAdd(&pool[NGRAPH * NEXP + t], gcnt[t]);
}

// ---------------- mean + blin + log_softmax -----------------------------------
__global__ void k_lsm(const float* __restrict__ pool, const float* __restrict__ blin,
                      float* __restrict__ out) {
    int g = threadIdx.x;
    if (g >= NGRAPH) return;
    float cnt = fmaxf(pool[NGRAPH * NEXP + g], 1.0f);
    float v[NEXP];
    float m = -1e30f;
#pragma unroll
    for (int k = 0; k < NEXP; k++) {
        v[k] = pool[g * NEXP + k] / cnt + blin[k];
        m = fmaxf(m, v[k]);
    }
    float s = 0.0f;
#pragma unroll
    for (int k = 0; k < NEXP; k++) s += expf(v[k] - m);
    float ls = logf(s);
#pragma unroll
    for (int k = 0; k < NEXP; k++) out[g * NEXP + k] = v[k] - m - ls;
}

extern "C" void kernel_launch(void* const* d_in, const int* in_sizes, int n_in,
                              void* d_out, int out_size, void* d_ws, size_t ws_size,
                              hipStream_t stream) {
    const float* an   = (const float*)d_in[0];
    const float* pos  = (const float*)d_in[1];
    const int*   ei   = (const int*)d_in[2];     // [2, E] flat
    const int*   batch= (const int*)d_in[3];
    const float* W1   = (const float*)d_in[4];
    const float* b1   = (const float*)d_in[5];
    const float* W2   = (const float*)d_in[6];
    const float* b2   = (const float*)d_in[7];
    const float* Wlin = (const float*)d_in[8];
    const float* blin = (const float*)d_in[9];
    float* out = (float*)d_out;

    const int n = in_sizes[0];
    const int e = in_sizes[2] / 2;
    const int* src = ei;
    const int* dst = ei + e;

    // workspace layout (bf16 buffers first for 16B alignment)
    char* p = (char*)d_ws;
    unsigned short* bufA = (unsigned short*)p;  p += sizeof(short) * (size_t)n * HID;
    unsigned short* bufB = (unsigned short*)p;  p += sizeof(short) * (size_t)n * HID;
    unsigned short* W2t  = (unsigned short*)p;  p += sizeof(short) * HID * HID;
    float* dinv = (float*)p;          p += sizeof(float) * (size_t)n;
    float* pool = (float*)p;          p += sizeof(float) * (NGRAPH * NEXP + NGRAPH);
    int*   cnt  = (int*)p;            p += sizeof(int) * (size_t)n;
    int*   off  = (int*)p;            p += sizeof(int) * (size_t)n;
    int*   cur  = (int*)p;            p += sizeof(int) * (size_t)n;
    int*   bsum = (int*)p;            p += sizeof(int) * 512;
    int*   eidx = (int*)p;            p += sizeof(int) * (size_t)e;

    const int nb256 = (n + 255) / 256;

    // CSR build (+dinv fused into scan)
    k_init<<<nb256, 256, 0, stream>>>(cnt, pool, n);
    k_cnt<<<(e + 255) / 256, 256, 0, stream>>>(dst, cnt, e);
    k_scan_block<<<nb256, 256, 0, stream>>>(cnt, off, bsum, dinv, n);
    k_scan_top<<<1, 512, 0, stream>>>(bsum, nb256);
    k_add_off<<<nb256, 256, 0, stream>>>(off, bsum, cur, n);
    k_fill<<<(e + 255) / 256, 256, 0, stream>>>(src, dst, cur, eidx, e);
    k_w2t<<<(HID * HID + 255) / 256, 256, 0, stream>>>(W2, W2t);

    // layer 1
    k_h1<<<(n + 3) / 4, 256, 0, stream>>>(an, pos, W1, dinv, (unsigned*)bufA, n);
    k_gather<<<(n + 3) / 4, 256, 0, stream>>>((const unsigned*)bufA, eidx, off, cnt,
                                              dinv, b1, (unsigned*)bufB, n, 1);
    // layer 2 (MFMA)
    k_h2<<<(n + 63) / 64, 256, 0, stream>>>(bufB, W2t, dinv, bufA, n);
    k_gather<<<(n + 3) / 4, 256, 0, stream>>>((const unsigned*)bufA, eidx, off, cnt,
                                              dinv, b2, (unsigned*)bufB, n, 0);
    // projection + pooling + log_softmax
    k_pool<<<(n + 127) / 128, 256, 0, stream>>>((const unsigned*)bufB, Wlin, batch, pool, n);
    k_lsm<<<1, 64, 0, stream>>>(pool, blin, out);
}

// Round 4
// 423.289 us; speedup vs baseline: 8.7151x; 1.2763x over previous
//
#include <hip/hip_runtime.h>
#include <math.h>

#define HID 128
#define NEXP 8
#define NGRAPH 64
#define EPC 16384      // edges per chunk (pass A blocks)
#define MAXB 512       // max coarse buckets (n <= 131072)

typedef __attribute__((ext_vector_type(8))) short short8;
typedef __attribute__((ext_vector_type(4))) float float4v;

__device__ inline unsigned short f2bf(float f) {
    unsigned u = __float_as_uint(f);
    u += 0x7FFF + ((u >> 16) & 1);          // RNE
    return (unsigned short)(u >> 16);
}
__device__ inline unsigned packbf(float lo, float hi) {
    return (unsigned)f2bf(lo) | ((unsigned)f2bf(hi) << 16);
}
__device__ inline float bflo(unsigned u) { return __uint_as_float(u << 16); }
__device__ inline float bfhi(unsigned u) { return __uint_as_float(u & 0xFFFF0000u); }

// ---------------- init: bcnt = 0, pool = 0 (one 1024-thread block) ------------
__global__ void k_init0(int* __restrict__ bcnt, float* __restrict__ pool, int nbuck) {
    int t = threadIdx.x;
    if (t < nbuck) bcnt[t] = 0;
    if (t < NGRAPH * NEXP + NGRAPH) pool[t] = 0.0f;
}

// ---------------- pass 0: per-chunk LDS histogram over coarse buckets ---------
__global__ void k_hist(const int* __restrict__ dst, int* __restrict__ runcnt,
                       int* __restrict__ bcnt, int e, int nbuck) {
    __shared__ int h[MAXB];
    int c = blockIdx.x, t = threadIdx.x;
    for (int b = t; b < nbuck; b += 256) h[b] = 0;
    __syncthreads();
    int start = c * EPC;
    int end = start + EPC < e ? start + EPC : e;
    for (int i = start + t; i < end; i += 256)
        atomicAdd(&h[dst[i] >> 8], 1);
    __syncthreads();
    for (int b = t; b < nbuck; b += 256) {
        runcnt[c * nbuck + b] = h[b];
        if (h[b]) atomicAdd(&bcnt[b], h[b]);
    }
}

// ---------------- bucket exclusive scan (<=512 buckets, 1 block) --------------
__global__ void k_cscan(const int* __restrict__ bcnt, int* __restrict__ boff,
                        int e, int nbuck) {
    __shared__ int s[512];
    int t = threadIdx.x;
    int v = (t < nbuck) ? bcnt[t] : 0;
    s[t] = v;
    __syncthreads();
    for (int d = 1; d < 512; d <<= 1) {
        int x = (t >= d) ? s[t - d] : 0;
        __syncthreads();
        s[t] += x;
        __syncthreads();
    }
    if (t < nbuck) boff[t] = s[t] - v;
    if (t == 0) boff[nbuck] = e;
}

// ---------------- column scan: runcnt[c][b] -> global run start ---------------
__global__ void k_colscan(int* __restrict__ runcnt, const int* __restrict__ boff,
                          int ch, int nbuck) {
    int b = threadIdx.x;
    if (b >= nbuck) return;
    int run = boff[b];
    for (int c0 = 0; c0 < ch; c0 += 8) {
        int v[8];
#pragma unroll
        for (int j = 0; j < 8; j++)
            v[j] = (c0 + j < ch) ? runcnt[(c0 + j) * nbuck + b] : 0;
#pragma unroll
        for (int j = 0; j < 8; j++) {
            if (c0 + j < ch) runcnt[(c0 + j) * nbuck + b] = run;
            run += v[j];
        }
    }
}

// ---------------- pass A: bin edges into bucket-contiguous order --------------
__global__ void k_binA(const int* __restrict__ src, const int* __restrict__ dst,
                       const int* __restrict__ runcnt, unsigned* __restrict__ binned,
                       int e, int nbuck) {
    __shared__ int cur[MAXB];
    int c = blockIdx.x, t = threadIdx.x;
    for (int b = t; b < nbuck; b += 256) cur[b] = runcnt[c * nbuck + b];
    __syncthreads();
    int start = c * EPC;
    int end = start + EPC < e ? start + EPC : e;
    for (int i = start + t; i < end; i += 256) {
        int d = dst[i];
        int p = atomicAdd(&cur[d >> 8], 1);
        binned[p] = ((unsigned)(d & 255) << 24) | (unsigned)src[i];
    }
}

// ---------------- pass B: per-bucket fine sort + cnt/off/dinv -----------------
__global__ void k_binB(const unsigned* __restrict__ binned, const int* __restrict__ boff,
                       int* __restrict__ cnt, int* __restrict__ off,
                       float* __restrict__ dinv, int* __restrict__ eidx, int n) {
    __shared__ int h[256];
    __shared__ int sc[256];
    __shared__ int cur[256];
    int b = blockIdx.x, t = threadIdx.x;
    int s0 = boff[b], s1 = boff[b + 1];
    h[t] = 0;
    __syncthreads();
    for (int k = s0 + t; k < s1; k += 256)
        atomicAdd(&h[binned[k] >> 24], 1);
    __syncthreads();
    int v = h[t];
    sc[t] = v;
    __syncthreads();
    for (int d = 1; d < 256; d <<= 1) {
        int x = (t >= d) ? sc[t - d] : 0;
        __syncthreads();
        sc[t] += x;
        __syncthreads();
    }
    int ex = sc[t] - v;          // exclusive within bucket
    cur[t] = ex;
    int node = (b << 8) + t;
    if (node < n) {
        cnt[node]  = v;
        off[node]  = s0 + ex;
        dinv[node] = rsqrtf((float)v + 1.0f);   // +1 = self-loop
    }
    __syncthreads();
    for (int k = s0 + t; k < s1; k += 256) {
        unsigned u = binned[k];
        int p = atomicAdd(&cur[u >> 24], 1);
        eidx[s0 + p] = (int)(u & 0xFFFFFF);
    }
}

// ---------------- W2 (fp32 [k][n]) -> W2t (bf16 [n][k]) ------------------------
__global__ void k_w2t(const float* __restrict__ W2, unsigned short* __restrict__ W2t) {
    int id = blockIdx.x * blockDim.x + threadIdx.x;
    if (id >= HID * HID) return;
    int k = id >> 7, nn = id & 127;
    W2t[nn * HID + k] = f2bf(W2[id]);
}

// ---------------- layer 1 dense: hs1 = (x@W1)*dinv, bf16 out -------------------
__global__ void k_h1(const float* __restrict__ an, const float* __restrict__ pos,
                     const float* __restrict__ W1, const float* __restrict__ dinv,
                     unsigned* __restrict__ hs1, int n) {
    int i = blockIdx.x * 4 + (threadIdx.x >> 6);
    if (i >= n) return;
    int p = threadIdx.x & 63;
    const float2* W1v = (const float2*)W1;
    float2 w0 = W1v[0 * 64 + p], w1 = W1v[1 * 64 + p],
           w2 = W1v[2 * 64 + p], w3 = W1v[3 * 64 + p];
    float x0 = an[i], px = pos[3 * i], py = pos[3 * i + 1], pz = pos[3 * i + 2];
    float di = dinv[i];
    float h0 = (x0 * w0.x + px * w1.x + py * w2.x + pz * w3.x) * di;
    float h1 = (x0 * w0.y + px * w1.y + py * w2.y + pz * w3.y) * di;
    hs1[(size_t)i * 64 + p] = packbf(h0, h1);
}

// ---------------- gather: out[i] = act(dinv[i]*(hs[i] + sum_src hs[src]) + b) --
__global__ void k_gather(const unsigned* __restrict__ hs, const int* __restrict__ eidx,
                         const int* __restrict__ off, const int* __restrict__ cnt,
                         const float* __restrict__ dinv, const float* __restrict__ b,
                         unsigned* __restrict__ out, int n, int relu) {
    int w = threadIdx.x >> 6;
    int lane = threadIdx.x & 63;
    int i = blockIdx.x * 4 + w;
    if (i >= n) return;
    unsigned u = hs[(size_t)i * 64 + lane];       // self-loop
    float a0 = bflo(u), a1 = bfhi(u);
    int o = off[i], c = cnt[i];
    int k = 0;
    for (; k + 4 <= c; k += 4) {
        int s0 = eidx[o + k], s1 = eidx[o + k + 1];
        int s2 = eidx[o + k + 2], s3 = eidx[o + k + 3];
        unsigned u0 = hs[(size_t)s0 * 64 + lane];
        unsigned u1 = hs[(size_t)s1 * 64 + lane];
        unsigned u2 = hs[(size_t)s2 * 64 + lane];
        unsigned u3 = hs[(size_t)s3 * 64 + lane];
        a0 += bflo(u0) + bflo(u1) + bflo(u2) + bflo(u3);
        a1 += bfhi(u0) + bfhi(u1) + bfhi(u2) + bfhi(u3);
    }
    for (; k < c; k++) {
        unsigned uu = hs[(size_t)eidx[o + k] * 64 + lane];
        a0 += bflo(uu);
        a1 += bfhi(uu);
    }
    float2 bb = ((const float2*)b)[lane];
    float di = dinv[i];
    float v0 = di * a0 + bb.x;
    float v1 = di * a1 + bb.y;
    if (relu) { v0 = fmaxf(v0, 0.0f); v1 = fmaxf(v1, 0.0f); }
    out[(size_t)i * 64 + lane] = packbf(v0, v1);
}

// ---------------- layer 2: hs2 = (x1@W2)*dinv via MFMA bf16 --------------------
#define W2PAD 136
__global__ void __launch_bounds__(256) k_h2(
        const unsigned short* __restrict__ x1, const unsigned short* __restrict__ W2t,
        const float* __restrict__ dinv, unsigned short* __restrict__ hs2, int n) {
    __shared__ short w2s[HID * W2PAD];
    int t = threadIdx.x;
    for (int it = 0; it < 8; it++) {
        int c8 = it * 256 + t;
        int row = c8 >> 4, ch = c8 & 15;
        *(short8*)&w2s[row * W2PAD + ch * 8] = ((const short8*)W2t)[row * 16 + ch];
    }
    __syncthreads();

    int w = t >> 6, l = t & 63;
    int lm = l & 15, lq = l >> 4;
    int base = blockIdx.x * 64 + w * 16;
    int arow = base + lm;
    int arow_c = arow < n ? arow : n - 1;
    const short8* xrow = (const short8*)(x1 + (size_t)arow_c * HID);
    short8 a0 = xrow[lq + 0], a1 = xrow[lq + 4], a2 = xrow[lq + 8], a3 = xrow[lq + 12];

    float4v acc[8];
#pragma unroll
    for (int nt = 0; nt < 8; nt++) acc[nt] = (float4v){0.f, 0.f, 0.f, 0.f};

#pragma unroll
    for (int nt = 0; nt < 8; nt++) {
        const short* bp = &w2s[(nt * 16 + lm) * W2PAD + lq * 8];
        short8 b0 = *(const short8*)(bp);
        short8 b1 = *(const short8*)(bp + 32);
        short8 b2 = *(const short8*)(bp + 64);
        short8 b3 = *(const short8*)(bp + 96);
        acc[nt] = __builtin_amdgcn_mfma_f32_16x16x32_bf16(a0, b0, acc[nt], 0, 0, 0);
        acc[nt] = __builtin_amdgcn_mfma_f32_16x16x32_bf16(a1, b1, acc[nt], 0, 0, 0);
        acc[nt] = __builtin_amdgcn_mfma_f32_16x16x32_bf16(a2, b2, acc[nt], 0, 0, 0);
        acc[nt] = __builtin_amdgcn_mfma_f32_16x16x32_bf16(a3, b3, acc[nt], 0, 0, 0);
    }

    float di[4];
    int orow[4];
#pragma unroll
    for (int r = 0; r < 4; r++) {
        orow[r] = base + lq * 4 + r;
        di[r] = dinv[orow[r] < n ? orow[r] : n - 1];
    }
#pragma unroll
    for (int nt = 0; nt < 8; nt++) {
#pragma unroll
        for (int r = 0; r < 4; r++) {
            if (orow[r] < n)
                hs2[(size_t)orow[r] * HID + nt * 16 + lm] = f2bf(acc[nt][r] * di[r]);
        }
    }
}

// ---------------- projection + hierarchical pooling (bf16 in) ------------------
__global__ void k_pool(const unsigned* __restrict__ x2, const float* __restrict__ Wlin,
                       const int* __restrict__ batch, float* __restrict__ pool, int n) {
    __shared__ float gsum[NGRAPH * NEXP];
    __shared__ float gcnt[NGRAPH];
    __shared__ int touched[NGRAPH];
    int t = threadIdx.x;
    for (int idx = t; idx < NGRAPH * NEXP; idx += 256) gsum[idx] = 0.0f;
    if (t < NGRAPH) { gcnt[t] = 0.0f; touched[t] = 0; }
    __syncthreads();

    int w = t >> 6;
    int lane = t & 63;
    float wl[NEXP], wh[NEXP];
#pragma unroll
    for (int k = 0; k < NEXP; k++) {
        wl[k] = Wlin[(2 * lane) * NEXP + k];
        wh[k] = Wlin[(2 * lane + 1) * NEXP + k];
    }
    int base = blockIdx.x * 128 + w * 32;
    for (int q = 0; q < 32; q++) {
        int i = base + q;
        if (i >= n) break;
        unsigned u = x2[(size_t)i * 64 + lane];
        float xa = bflo(u), xb = bfhi(u);
        float p[NEXP];
#pragma unroll
        for (int k = 0; k < NEXP; k++) p[k] = xa * wl[k] + xb * wh[k];
#pragma unroll
        for (int offd = 32; offd > 0; offd >>= 1) {
#pragma unroll
            for (int k = 0; k < NEXP; k++) p[k] += __shfl_down(p[k], offd, 64);
        }
        if (lane == 0) {
            int g = batch[i];
            touched[g] = 1;
#pragma unroll
            for (int k = 0; k < NEXP; k++) atomicAdd(&gsum[g * NEXP + k], p[k]);
            atomicAdd(&gcnt[g], 1.0f);
        }
    }
    __syncthreads();
    for (int idx = t; idx < NGRAPH * NEXP; idx += 256) {
        int g = idx >> 3;
        if (touched[g]) atomicAdd(&pool[idx], gsum[idx]);
    }
    if (t < NGRAPH && touched[t]) atomicAdd(&pool[NGRAPH * NEXP + t], gcnt[t]);
}

// ---------------- mean + blin + log_softmax -----------------------------------
__global__ void k_lsm(const float* __restrict__ pool, const float* __restrict__ blin,
                      float* __restrict__ out) {
    int g = threadIdx.x;
    if (g >= NGRAPH) return;
    float cnt = fmaxf(pool[NGRAPH * NEXP + g], 1.0f);
    float v[NEXP];
    float m = -1e30f;
#pragma unroll
    for (int k = 0; k < NEXP; k++) {
        v[k] = pool[g * NEXP + k] / cnt + blin[k];
        m = fmaxf(m, v[k]);
    }
    float s = 0.0f;
#pragma unroll
    for (int k = 0; k < NEXP; k++) s += expf(v[k] - m);
    float ls = logf(s);
#pragma unroll
    for (int k = 0; k < NEXP; k++) out[g * NEXP + k] = v[k] - m - ls;
}

extern "C" void kernel_launch(void* const* d_in, const int* in_sizes, int n_in,
                              void* d_out, int out_size, void* d_ws, size_t ws_size,
                              hipStream_t stream) {
    const float* an   = (const float*)d_in[0];
    const float* pos  = (const float*)d_in[1];
    const int*   ei   = (const int*)d_in[2];     // [2, E] flat (int32 view)
    const int*   batch= (const int*)d_in[3];
    const float* W1   = (const float*)d_in[4];
    const float* b1   = (const float*)d_in[5];
    const float* W2   = (const float*)d_in[6];
    const float* b2   = (const float*)d_in[7];
    const float* Wlin = (const float*)d_in[8];
    const float* blin = (const float*)d_in[9];
    float* out = (float*)d_out;

    const int n = in_sizes[0];
    const int e = in_sizes[2] / 2;
    const int* src = ei;
    const int* dst = ei + e;

    const int nbuck = (n + 255) >> 8;            // coarse buckets (<= MAXB)
    const int ch    = (e + EPC - 1) / EPC;       // chunks

    // workspace layout (16B-aligned bf16 buffers first)
    char* p = (char*)d_ws;
    unsigned short* bufA = (unsigned short*)p;  p += sizeof(short) * (size_t)n * HID;
    unsigned short* bufB = (unsigned short*)p;  p += sizeof(short) * (size_t)n * HID;
    unsigned short* W2t  = (unsigned short*)p;  p += sizeof(short) * HID * HID;
    float* dinv   = (float*)p;        p += sizeof(float) * (size_t)n;
    float* pool   = (float*)p;        p += sizeof(float) * (NGRAPH * NEXP + NGRAPH);
    int*   cnt    = (int*)p;          p += sizeof(int) * (size_t)n;
    int*   off    = (int*)p;          p += sizeof(int) * (size_t)n;
    int*   bcnt   = (int*)p;          p += sizeof(int) * (MAXB + 1);
    int*   boff   = (int*)p;          p += sizeof(int) * (MAXB + 1);
    int*   runcnt = (int*)p;          p += sizeof(int) * (size_t)ch * nbuck;
    unsigned* binned = (unsigned*)p;  p += sizeof(unsigned) * (size_t)e;
    int*   eidx   = (int*)p;          p += sizeof(int) * (size_t)e;

    // CSR build via two-phase counting sort
    k_init0<<<1, 1024, 0, stream>>>(bcnt, pool, nbuck);
    k_hist<<<ch, 256, 0, stream>>>(dst, runcnt, bcnt, e, nbuck);
    k_cscan<<<1, 512, 0, stream>>>(bcnt, boff, e, nbuck);
    k_colscan<<<1, 512, 0, stream>>>(runcnt, boff, ch, nbuck);
    k_binA<<<ch, 256, 0, stream>>>(src, dst, runcnt, binned, e, nbuck);
    k_binB<<<nbuck, 256, 0, stream>>>(binned, boff, cnt, off, dinv, eidx, n);
    k_w2t<<<(HID * HID + 255) / 256, 256, 0, stream>>>(W2, W2t);

    // layer 1
    k_h1<<<(n + 3) / 4, 256, 0, stream>>>(an, pos, W1, dinv, (unsigned*)bufA, n);
    k_gather<<<(n + 3) / 4, 256, 0, stream>>>((const unsigned*)bufA, eidx, off, cnt,
                                              dinv, b1, (unsigned*)bufB, n, 1);
    // layer 2 (MFMA)
    k_h2<<<(n + 63) / 64, 256, 0, stream>>>(bufB, W2t, dinv, bufA, n);
    k_gather<<<(n + 3) / 4, 256, 0, stream>>>((const unsigned*)bufA, eidx, off, cnt,
                                              dinv, b2, (unsigned*)bufB, n, 0);
    // projection + pooling + log_softmax
    k_pool<<<(n + 127) / 128, 256, 0, stream>>>((const unsigned*)bufB, Wlin, batch, pool, n);
    k_lsm<<<1, 64, 0, stream>>>(pool, blin, out);
}

// Round 5
// 375.661 us; speedup vs baseline: 9.8201x; 1.1268x over previous
//
#include <hip/hip_runtime.h>
#include <math.h>

#define HID 128
#define NEXP 8
#define NGRAPH 64
#define EPC 16384      // edges per chunk (pass A blocks)
#define MAXB 512       // max coarse buckets (n <= 131072)
#define NREP 8         // pool replicas (atomic-contention spreading)

typedef __attribute__((ext_vector_type(8))) short short8;
typedef __attribute__((ext_vector_type(4))) float float4v;

__device__ inline unsigned short f2bf(float f) {
    unsigned u = __float_as_uint(f);
    u += 0x7FFF + ((u >> 16) & 1);          // RNE
    return (unsigned short)(u >> 16);
}
__device__ inline unsigned packbf(float lo, float hi) {
    return (unsigned)f2bf(lo) | ((unsigned)f2bf(hi) << 16);
}
__device__ inline float bflo(unsigned u) { return __uint_as_float(u << 16); }
__device__ inline float bfhi(unsigned u) { return __uint_as_float(u & 0xFFFF0000u); }

// ---------------- init: bcnt, pool replicas, pcnt -----------------------------
__global__ void k_init0(int* __restrict__ bcnt, float* __restrict__ pool,
                        float* __restrict__ pcnt, int nbuck) {
    int i = blockIdx.x * 256 + threadIdx.x;
    if (i < nbuck) bcnt[i] = 0;
    if (i < NREP * NGRAPH * HID) pool[i] = 0.0f;
    if (i < NREP * NGRAPH) pcnt[i] = 0.0f;
}

// ---------------- pass 0: per-chunk LDS histogram over coarse buckets ---------
__global__ void k_hist(const int* __restrict__ dst, int* __restrict__ runcnt,
                       int* __restrict__ bcnt, int e, int nbuck) {
    __shared__ int h[MAXB];
    int c = blockIdx.x, t = threadIdx.x;
    for (int b = t; b < nbuck; b += 256) h[b] = 0;
    __syncthreads();
    int start = c * EPC;
    int end = start + EPC < e ? start + EPC : e;
    for (int i = start + t; i < end; i += 256)
        atomicAdd(&h[dst[i] >> 8], 1);
    __syncthreads();
    for (int b = t; b < nbuck; b += 256) {
        runcnt[c * nbuck + b] = h[b];
        if (h[b]) atomicAdd(&bcnt[b], h[b]);
    }
}

// ---------------- bucket exclusive scan (<=512 buckets, 1 block) --------------
__global__ void k_cscan(const int* __restrict__ bcnt, int* __restrict__ boff,
                        int e, int nbuck) {
    __shared__ int s[512];
    int t = threadIdx.x;
    int v = (t < nbuck) ? bcnt[t] : 0;
    s[t] = v;
    __syncthreads();
    for (int d = 1; d < 512; d <<= 1) {
        int x = (t >= d) ? s[t - d] : 0;
        __syncthreads();
        s[t] += x;
        __syncthreads();
    }
    if (t < nbuck) boff[t] = s[t] - v;
    if (t == 0) boff[nbuck] = e;
}

// ---------------- column scan: runcnt[c][b] -> global run start ---------------
__global__ void k_colscan(int* __restrict__ runcnt, const int* __restrict__ boff,
                          int ch, int nbuck) {
    int b = threadIdx.x;
    if (b >= nbuck) return;
    int run = boff[b];
    for (int c0 = 0; c0 < ch; c0 += 8) {
        int v[8];
#pragma unroll
        for (int j = 0; j < 8; j++)
            v[j] = (c0 + j < ch) ? runcnt[(c0 + j) * nbuck + b] : 0;
#pragma unroll
        for (int j = 0; j < 8; j++) {
            if (c0 + j < ch) runcnt[(c0 + j) * nbuck + b] = run;
            run += v[j];
        }
    }
}

// ---------------- pass A: bin edges into bucket-contiguous order --------------
__global__ void k_binA(const int* __restrict__ src, const int* __restrict__ dst,
                       const int* __restrict__ runcnt, unsigned* __restrict__ binned,
                       int e, int nbuck) {
    __shared__ int cur[MAXB];
    int c = blockIdx.x, t = threadIdx.x;
    for (int b = t; b < nbuck; b += 256) cur[b] = runcnt[c * nbuck + b];
    __syncthreads();
    int start = c * EPC;
    int end = start + EPC < e ? start + EPC : e;
    for (int i = start + t; i < end; i += 256) {
        int d = dst[i];
        int p = atomicAdd(&cur[d >> 8], 1);
        binned[p] = ((unsigned)(d & 255) << 24) | (unsigned)src[i];
    }
}

// ---------------- pass B: per-bucket fine sort + cnt/off/dinv -----------------
__global__ void k_binB(const unsigned* __restrict__ binned, const int* __restrict__ boff,
                       int* __restrict__ cnt, int* __restrict__ off,
                       float* __restrict__ dinv, int* __restrict__ eidx, int n) {
    __shared__ int h[256];
    __shared__ int sc[256];
    __shared__ int cur[256];
    int b = blockIdx.x, t = threadIdx.x;
    int s0 = boff[b], s1 = boff[b + 1];
    h[t] = 0;
    __syncthreads();
    for (int k = s0 + t; k < s1; k += 256)
        atomicAdd(&h[binned[k] >> 24], 1);
    __syncthreads();
    int v = h[t];
    sc[t] = v;
    __syncthreads();
    for (int d = 1; d < 256; d <<= 1) {
        int x = (t >= d) ? sc[t - d] : 0;
        __syncthreads();
        sc[t] += x;
        __syncthreads();
    }
    int ex = sc[t] - v;          // exclusive within bucket
    cur[t] = ex;
    int node = (b << 8) + t;
    if (node < n) {
        cnt[node]  = v;
        off[node]  = s0 + ex;
        dinv[node] = rsqrtf((float)v + 1.0f);   // +1 = self-loop
    }
    __syncthreads();
    for (int k = s0 + t; k < s1; k += 256) {
        unsigned u = binned[k];
        int p = atomicAdd(&cur[u >> 24], 1);
        eidx[s0 + p] = (int)(u & 0xFFFFFF);
    }
}

// ---------------- W2 (fp32 [k][n]) -> W2t (bf16 [n][k]) ------------------------
__global__ void k_w2t(const float* __restrict__ W2, unsigned short* __restrict__ W2t) {
    int id = blockIdx.x * blockDim.x + threadIdx.x;
    if (id >= HID * HID) return;
    int k = id >> 7, nn = id & 127;
    W2t[nn * HID + k] = f2bf(W2[id]);
}

// ---------------- layer 1 dense: hs1 = (x@W1)*dinv, bf16 out -------------------
__global__ void k_h1(const float* __restrict__ an, const float* __restrict__ pos,
                     const float* __restrict__ W1, const float* __restrict__ dinv,
                     unsigned* __restrict__ hs1, int n) {
    int i = blockIdx.x * 4 + (threadIdx.x >> 6);
    if (i >= n) return;
    int p = threadIdx.x & 63;
    const float2* W1v = (const float2*)W1;
    float2 w0 = W1v[0 * 64 + p], w1 = W1v[1 * 64 + p],
           w2 = W1v[2 * 64 + p], w3 = W1v[3 * 64 + p];
    float x0 = an[i], px = pos[3 * i], py = pos[3 * i + 1], pz = pos[3 * i + 2];
    float di = dinv[i];
    float h0 = (x0 * w0.x + px * w1.x + py * w2.x + pz * w3.x) * di;
    float h1 = (x0 * w0.y + px * w1.y + py * w2.y + pz * w3.y) * di;
    hs1[(size_t)i * 64 + p] = packbf(h0, h1);
}

// ---------------- edge accumulate helper (8-unrolled) --------------------------
__device__ inline void edge_acc(const unsigned* __restrict__ hs,
                                const int* __restrict__ eidx,
                                int o, int c, int lane, float& a0, float& a1) {
    int k = 0;
    for (; k + 8 <= c; k += 8) {
        unsigned uu[8];
#pragma unroll
        for (int j = 0; j < 8; j++)
            uu[j] = hs[(size_t)eidx[o + k + j] * 64 + lane];
#pragma unroll
        for (int j = 0; j < 8; j++) { a0 += bflo(uu[j]); a1 += bfhi(uu[j]); }
    }
    for (; k < c; k++) {
        unsigned uu = hs[(size_t)eidx[o + k] * 64 + lane];
        a0 += bflo(uu);
        a1 += bfhi(uu);
    }
}

// ---------------- gather1: x1 = relu(dinv*(hs+sum)+b1), bf16 out ---------------
__global__ void k_gather(const unsigned* __restrict__ hs, const int* __restrict__ eidx,
                         const int* __restrict__ off, const int* __restrict__ cnt,
                         const float* __restrict__ dinv, const float* __restrict__ b,
                         unsigned* __restrict__ out, int n) {
    int w = threadIdx.x >> 6;
    int lane = threadIdx.x & 63;
    int i = blockIdx.x * 4 + w;
    if (i >= n) return;
    unsigned u = hs[(size_t)i * 64 + lane];       // self-loop
    float a0 = bflo(u), a1 = bfhi(u);
    edge_acc(hs, eidx, off[i], cnt[i], lane, a0, a1);
    float2 bb = ((const float2*)b)[lane];
    float di = dinv[i];
    float v0 = fmaxf(di * a0 + bb.x, 0.0f);
    float v1 = fmaxf(di * a1 + bb.y, 0.0f);
    out[(size_t)i * 64 + lane] = packbf(v0, v1);
}

// ---------------- layer 2: hs2 = (x1@W2)*dinv via MFMA bf16 --------------------
#define W2PAD 136
__global__ void __launch_bounds__(256) k_h2(
        const unsigned short* __restrict__ x1, const unsigned short* __restrict__ W2t,
        const float* __restrict__ dinv, unsigned short* __restrict__ hs2, int n) {
    __shared__ short w2s[HID * W2PAD];
    int t = threadIdx.x;
    for (int it = 0; it < 8; it++) {
        int c8 = it * 256 + t;
        int row = c8 >> 4, ch = c8 & 15;
        *(short8*)&w2s[row * W2PAD + ch * 8] = ((const short8*)W2t)[row * 16 + ch];
    }
    __syncthreads();

    int w = t >> 6, l = t & 63;
    int lm = l & 15, lq = l >> 4;
    int base = blockIdx.x * 64 + w * 16;
    int arow = base + lm;
    int arow_c = arow < n ? arow : n - 1;
    const short8* xrow = (const short8*)(x1 + (size_t)arow_c * HID);
    short8 a0 = xrow[lq + 0], a1 = xrow[lq + 4], a2 = xrow[lq + 8], a3 = xrow[lq + 12];

    float4v acc[8];
#pragma unroll
    for (int nt = 0; nt < 8; nt++) acc[nt] = (float4v){0.f, 0.f, 0.f, 0.f};

#pragma unroll
    for (int nt = 0; nt < 8; nt++) {
        const short* bp = &w2s[(nt * 16 + lm) * W2PAD + lq * 8];
        short8 b0 = *(const short8*)(bp);
        short8 b1 = *(const short8*)(bp + 32);
        short8 b2 = *(const short8*)(bp + 64);
        short8 b3 = *(const short8*)(bp + 96);
        acc[nt] = __builtin_amdgcn_mfma_f32_16x16x32_bf16(a0, b0, acc[nt], 0, 0, 0);
        acc[nt] = __builtin_amdgcn_mfma_f32_16x16x32_bf16(a1, b1, acc[nt], 0, 0, 0);
        acc[nt] = __builtin_amdgcn_mfma_f32_16x16x32_bf16(a2, b2, acc[nt], 0, 0, 0);
        acc[nt] = __builtin_amdgcn_mfma_f32_16x16x32_bf16(a3, b3, acc[nt], 0, 0, 0);
    }

    float di[4];
    int orow[4];
#pragma unroll
    for (int r = 0; r < 4; r++) {
        orow[r] = base + lq * 4 + r;
        di[r] = dinv[orow[r] < n ? orow[r] : n - 1];
    }
#pragma unroll
    for (int nt = 0; nt < 8; nt++) {
#pragma unroll
        for (int r = 0; r < 4; r++) {
            if (orow[r] < n)
                hs2[(size_t)orow[r] * HID + nt * 16 + lm] = f2bf(acc[nt][r] * di[r]);
        }
    }
}

// ---------------- fused gather2 + segment pooling ------------------------------
// one wave per 16 consecutive nodes; x2 row computed in registers, accumulated
// per batch-segment (batch sorted), flushed to replicated pool via atomics.
__global__ void k_gp(const unsigned* __restrict__ hs, const int* __restrict__ eidx,
                     const int* __restrict__ off, const int* __restrict__ cnt,
                     const float* __restrict__ dinv, const float* __restrict__ b,
                     const int* __restrict__ batch, float* __restrict__ pool,
                     float* __restrict__ pcnt, int n) {
    int w = threadIdx.x >> 6;
    int lane = threadIdx.x & 63;
    int base = blockIdx.x * 64 + w * 16;
    if (base >= n) return;
    int lim = base + 16 < n ? base + 16 : n;
    float2 bb = ((const float2*)b)[lane];
    float* rp  = pool + (size_t)(blockIdx.x & (NREP - 1)) * NGRAPH * HID;
    float* rpc = pcnt + (size_t)(blockIdx.x & (NREP - 1)) * NGRAPH;

    int curg = -1;
    float r0 = 0.0f, r1 = 0.0f, runlen = 0.0f;
    for (int i = base; i < lim; i++) {
        unsigned u = hs[(size_t)i * 64 + lane];   // self-loop
        float a0 = bflo(u), a1 = bfhi(u);
        edge_acc(hs, eidx, off[i], cnt[i], lane, a0, a1);
        float di = dinv[i];
        float v0 = di * a0 + bb.x;
        float v1 = di * a1 + bb.y;
        int g = batch[i];
        if (g != curg) {                           // wave-uniform branch
            if (curg >= 0) {
                atomicAdd(&rp[curg * HID + 2 * lane], r0);
                atomicAdd(&rp[curg * HID + 2 * lane + 1], r1);
                if (lane == 0) atomicAdd(&rpc[curg], runlen);
            }
            curg = g; r0 = v0; r1 = v1; runlen = 1.0f;
        } else { r0 += v0; r1 += v1; runlen += 1.0f; }
    }
    if (curg >= 0) {
        atomicAdd(&rp[curg * HID + 2 * lane], r0);
        atomicAdd(&rp[curg * HID + 2 * lane + 1], r1);
        if (lane == 0) atomicAdd(&rpc[curg], runlen);
    }
}

// ---------------- replica-sum + Wlin projection + mean + log_softmax ----------
// one block, 4 waves; wave w handles graphs w*16..w*16+15.
__global__ void k_lsm(const float* __restrict__ pool, const float* __restrict__ pcnt,
                      const float* __restrict__ Wlin, const float* __restrict__ blin,
                      float* __restrict__ out) {
    int w = threadIdx.x >> 6;
    int lane = threadIdx.x & 63;
    float wl[NEXP], wh[NEXP];
#pragma unroll
    for (int k = 0; k < NEXP; k++) {
        wl[k] = Wlin[(2 * lane) * NEXP + k];
        wh[k] = Wlin[(2 * lane + 1) * NEXP + k];
    }
    for (int q = 0; q < 16; q++) {
        int g = w * 16 + q;
        float s0 = 0.0f, s1 = 0.0f, cg = 0.0f;
#pragma unroll
        for (int r = 0; r < NREP; r++) {
            const float2 v = ((const float2*)(pool + (size_t)r * NGRAPH * HID + g * HID))[lane];
            s0 += v.x; s1 += v.y;
            cg += pcnt[r * NGRAPH + g];
        }
        float p[NEXP];
#pragma unroll
        for (int k = 0; k < NEXP; k++) p[k] = s0 * wl[k] + s1 * wh[k];
#pragma unroll
        for (int offd = 32; offd > 0; offd >>= 1) {
#pragma unroll
            for (int k = 0; k < NEXP; k++) p[k] += __shfl_down(p[k], offd, 64);
        }
        if (lane == 0) {
            float inv = 1.0f / fmaxf(cg, 1.0f);
            float v[NEXP], m = -1e30f;
#pragma unroll
            for (int k = 0; k < NEXP; k++) {
                v[k] = p[k] * inv + blin[k];
                m = fmaxf(m, v[k]);
            }
            float s = 0.0f;
#pragma unroll
            for (int k = 0; k < NEXP; k++) s += expf(v[k] - m);
            float ls = logf(s);
#pragma unroll
            for (int k = 0; k < NEXP; k++) out[g * NEXP + k] = v[k] - m - ls;
        }
    }
}

extern "C" void kernel_launch(void* const* d_in, const int* in_sizes, int n_in,
                              void* d_out, int out_size, void* d_ws, size_t ws_size,
                              hipStream_t stream) {
    const float* an   = (const float*)d_in[0];
    const float* pos  = (const float*)d_in[1];
    const int*   ei   = (const int*)d_in[2];     // [2, E] flat (int32 view)
    const int*   batch= (const int*)d_in[3];
    const float* W1   = (const float*)d_in[4];
    const float* b1   = (const float*)d_in[5];
    const float* W2   = (const float*)d_in[6];
    const float* b2   = (const float*)d_in[7];
    const float* Wlin = (const float*)d_in[8];
    const float* blin = (const float*)d_in[9];
    float* out = (float*)d_out;

    const int n = in_sizes[0];
    const int e = in_sizes[2] / 2;
    const int* src = ei;
    const int* dst = ei + e;

    const int nbuck = (n + 255) >> 8;            // coarse buckets (<= MAXB)
    const int ch    = (e + EPC - 1) / EPC;       // chunks

    // workspace layout (16B-aligned bf16 buffers first)
    char* p = (char*)d_ws;
    unsigned short* bufA = (unsigned short*)p;  p += sizeof(short) * (size_t)n * HID;
    unsigned short* bufB = (unsigned short*)p;  p += sizeof(short) * (size_t)n * HID;
    unsigned short* W2t  = (unsigned short*)p;  p += sizeof(short) * HID * HID;
    float* dinv   = (float*)p;        p += sizeof(float) * (size_t)n;
    float* pool   = (float*)p;        p += sizeof(float) * NREP * NGRAPH * HID;
    float* pcnt   = (float*)p;        p += sizeof(float) * NREP * NGRAPH;
    int*   cnt    = (int*)p;          p += sizeof(int) * (size_t)n;
    int*   off    = (int*)p;          p += sizeof(int) * (size_t)n;
    int*   bcnt   = (int*)p;          p += sizeof(int) * (MAXB + 1);
    int*   boff   = (int*)p;          p += sizeof(int) * (MAXB + 1);
    int*   runcnt = (int*)p;          p += sizeof(int) * (size_t)ch * nbuck;
    unsigned* binned = (unsigned*)p;  p += sizeof(unsigned) * (size_t)e;
    int*   eidx   = (int*)p;          p += sizeof(int) * (size_t)e;

    // CSR build via two-phase counting sort
    k_init0<<<(NREP * NGRAPH * HID + 255) / 256, 256, 0, stream>>>(bcnt, pool, pcnt, nbuck);
    k_hist<<<ch, 256, 0, stream>>>(dst, runcnt, bcnt, e, nbuck);
    k_cscan<<<1, 512, 0, stream>>>(bcnt, boff, e, nbuck);
    k_colscan<<<1, 512, 0, stream>>>(runcnt, boff, ch, nbuck);
    k_binA<<<ch, 256, 0, stream>>>(src, dst, runcnt, binned, e, nbuck);
    k_binB<<<nbuck, 256, 0, stream>>>(binned, boff, cnt, off, dinv, eidx, n);
    k_w2t<<<(HID * HID + 255) / 256, 256, 0, stream>>>(W2, W2t);

    // layer 1
    k_h1<<<(n + 3) / 4, 256, 0, stream>>>(an, pos, W1, dinv, (unsigned*)bufA, n);
    k_gather<<<(n + 3) / 4, 256, 0, stream>>>((const unsigned*)bufA, eidx, off, cnt,
                                              dinv, b1, (unsigned*)bufB, n);
    // layer 2 (MFMA)
    k_h2<<<(n + 63) / 64, 256, 0, stream>>>(bufB, W2t, dinv, bufA, n);

    // fused gather2 + pooling, then projection + log_softmax
    k_gp<<<(n + 63) / 64, 256, 0, stream>>>((const unsigned*)bufA, eidx, off, cnt,
                                            dinv, b2, batch, pool, pcnt, n);
    k_lsm<<<1, 256, 0, stream>>>(pool, pcnt, Wlin, blin, out);
}

// Round 6
// 330.016 us; speedup vs baseline: 11.1783x; 1.1383x over previous
//
#include <hip/hip_runtime.h>
#include <math.h>

#define HID 128
#define NEXP 8
#define NGRAPH 64
#define EPC 16384      // edges per chunk (pass A blocks)
#define MAXB 512       // max coarse buckets (n <= 131072)
#define NREP 8         // pool replicas (atomic-contention spreading)

typedef __attribute__((ext_vector_type(8))) short short8;
typedef __attribute__((ext_vector_type(4))) float float4v;
typedef __attribute__((ext_vector_type(2))) float floatx2;

__device__ inline unsigned short f2bf(float f) {
    unsigned u = __float_as_uint(f);
    u += 0x7FFF + ((u >> 16) & 1);          // RNE
    return (unsigned short)(u >> 16);
}
__device__ inline unsigned packbf(float lo, float hi) {
    return (unsigned)f2bf(lo) | ((unsigned)f2bf(hi) << 16);
}
__device__ inline unsigned char f2fp8(float v) {
    int pk = __builtin_amdgcn_cvt_pk_fp8_f32(v, v, 0, false);
    return (unsigned char)(pk & 0xFF);
}

// ---------------- init: pool/pcnt zero + W2 -> W2t (bf16 [n][k]) ---------------
__global__ void k_init0(float* __restrict__ pool, float* __restrict__ pcnt,
                        const float* __restrict__ W2, unsigned short* __restrict__ W2t) {
    int i = blockIdx.x * 256 + threadIdx.x;
    if (i < NREP * NGRAPH * HID) pool[i] = 0.0f;
    if (i < NREP * NGRAPH) pcnt[i] = 0.0f;
    if (i < HID * HID) {
        int k = i >> 7, nn = i & 127;
        W2t[nn * HID + k] = f2bf(W2[i]);
    }
}

// ---------------- pass 0: per-chunk LDS histogram over coarse buckets ---------
__global__ void k_hist(const int* __restrict__ dst, int* __restrict__ runcnt,
                       int e, int nbuck) {
    __shared__ int h[MAXB];
    int c = blockIdx.x, t = threadIdx.x;
    for (int b = t; b < nbuck; b += 256) h[b] = 0;
    __syncthreads();
    int start = c * EPC;
    int end = start + EPC < e ? start + EPC : e;
    for (int i = start + t; i < end; i += 256)
        atomicAdd(&h[dst[i] >> 8], 1);
    __syncthreads();
    for (int b = t; b < nbuck; b += 256)
        runcnt[c * nbuck + b] = h[b];
}

// ---------------- scan2: bucket totals + boff scan + runcnt -> global offsets --
__global__ void k_scan2(int* __restrict__ runcnt, int* __restrict__ boff,
                        int e, int ch, int nbuck) {
    __shared__ int s[512];
    int t = threadIdx.x;
    int tot = 0;
    if (t < nbuck)
        for (int c = 0; c < ch; c++) tot += runcnt[c * nbuck + t];
    s[t] = tot;
    __syncthreads();
    for (int d = 1; d < 512; d <<= 1) {
        int x = (t >= d) ? s[t - d] : 0;
        __syncthreads();
        s[t] += x;
        __syncthreads();
    }
    if (t < nbuck) {
        int run = s[t] - tot;               // exclusive
        boff[t] = run;
        for (int c = 0; c < ch; c++) {
            int v = runcnt[c * nbuck + t];
            runcnt[c * nbuck + t] = run;
            run += v;
        }
    }
    if (t == 0) boff[nbuck] = e;
}

// ---------------- pass A: bin edges into bucket-contiguous order --------------
__global__ void k_binA(const int* __restrict__ src, const int* __restrict__ dst,
                       const int* __restrict__ runcnt, unsigned* __restrict__ binned,
                       int e, int nbuck) {
    __shared__ int cur[MAXB];
    int c = blockIdx.x, t = threadIdx.x;
    for (int b = t; b < nbuck; b += 256) cur[b] = runcnt[c * nbuck + b];
    __syncthreads();
    int start = c * EPC;
    int end = start + EPC < e ? start + EPC : e;
    for (int i = start + t; i < end; i += 256) {
        int d = dst[i];
        int p = atomicAdd(&cur[d >> 8], 1);
        binned[p] = ((unsigned)(d & 255) << 24) | (unsigned)src[i];
    }
}

// ---------------- pass B: per-bucket fine sort + cnt/off/dinv + xs -------------
__global__ void k_binB(const unsigned* __restrict__ binned, const int* __restrict__ boff,
                       const float* __restrict__ an, const float* __restrict__ pos,
                       int* __restrict__ cnt, int* __restrict__ off,
                       float* __restrict__ dinv, float4* __restrict__ xs,
                       int* __restrict__ eidx, int n) {
    __shared__ int h[256];
    __shared__ int sc[256];
    __shared__ int cur[256];
    int b = blockIdx.x, t = threadIdx.x;
    int s0 = boff[b], s1 = boff[b + 1];
    h[t] = 0;
    __syncthreads();
    for (int k = s0 + t; k < s1; k += 256)
        atomicAdd(&h[binned[k] >> 24], 1);
    __syncthreads();
    int v = h[t];
    sc[t] = v;
    __syncthreads();
    for (int d = 1; d < 256; d <<= 1) {
        int x = (t >= d) ? sc[t - d] : 0;
        __syncthreads();
        sc[t] += x;
        __syncthreads();
    }
    int ex = sc[t] - v;          // exclusive within bucket
    cur[t] = ex;
    int node = (b << 8) + t;
    if (node < n) {
        float di = rsqrtf((float)v + 1.0f);   // +1 = self-loop
        cnt[node]  = v;
        off[node]  = s0 + ex;
        dinv[node] = di;
        xs[node] = make_float4(an[node] * di, pos[3 * node] * di,
                               pos[3 * node + 1] * di, pos[3 * node + 2] * di);
    }
    __syncthreads();
    for (int k = s0 + t; k < s1; k += 256) {
        unsigned u = binned[k];
        int p = atomicAdd(&cur[u >> 24], 1);
        eidx[s0 + p] = (int)(u & 0xFFFFFF);
    }
}

// ---------------- layer-1 gather in 4-dim space: agg4 = xs[i] + sum xs[src] ----
__global__ void k_gx(const float4* __restrict__ xs, const int* __restrict__ eidx,
                     const int* __restrict__ off, const int* __restrict__ cnt,
                     float4* __restrict__ agg4, int n) {
    int i = blockIdx.x * 256 + threadIdx.x;
    if (i >= n) return;
    float4 a = xs[i];                       // self-loop
    int o = off[i], c = cnt[i];
    int k = 0;
    for (; k + 8 <= c; k += 8) {
        int id[8];
#pragma unroll
        for (int j = 0; j < 8; j++) id[j] = eidx[o + k + j];
        float4 vv[8];
#pragma unroll
        for (int j = 0; j < 8; j++) vv[j] = xs[id[j]];
#pragma unroll
        for (int j = 0; j < 8; j++) {
            a.x += vv[j].x; a.y += vv[j].y; a.z += vv[j].z; a.w += vv[j].w;
        }
    }
    for (; k < c; k++) {
        float4 vv = xs[eidx[o + k]];
        a.x += vv.x; a.y += vv.y; a.z += vv.z; a.w += vv.w;
    }
    agg4[i] = a;
}

// ---------------- layer 1 dense: x1 = relu(dinv*(agg4@W1)+b1), bf16 out --------
__global__ void k_h1(const float4* __restrict__ agg4, const float* __restrict__ W1,
                     const float* __restrict__ b1, const float* __restrict__ dinv,
                     unsigned* __restrict__ x1, int n) {
    int i = blockIdx.x * 4 + (threadIdx.x >> 6);
    if (i >= n) return;
    int p = threadIdx.x & 63;
    const float2* W1v = (const float2*)W1;
    float2 w0 = W1v[0 * 64 + p], w1 = W1v[1 * 64 + p],
           w2 = W1v[2 * 64 + p], w3 = W1v[3 * 64 + p];
    float4 a = agg4[i];
    float di = dinv[i];
    float2 bb = ((const float2*)b1)[p];
    float h0 = fmaxf(di * (a.x * w0.x + a.y * w1.x + a.z * w2.x + a.w * w3.x) + bb.x, 0.0f);
    float h1 = fmaxf(di * (a.x * w0.y + a.y * w1.y + a.z * w2.y + a.w * w3.y) + bb.y, 0.0f);
    x1[(size_t)i * 64 + p] = packbf(h0, h1);
}

// ---------------- layer 2: hs2 = (x1@W2)*dinv via MFMA, fp8 e4m3 out -----------
#define W2PAD 136
__global__ void __launch_bounds__(256) k_h2(
        const unsigned short* __restrict__ x1, const unsigned short* __restrict__ W2t,
        const float* __restrict__ dinv, unsigned char* __restrict__ hs2, int n) {
    __shared__ short w2s[HID * W2PAD];
    int t = threadIdx.x;
    for (int it = 0; it < 8; it++) {
        int c8 = it * 256 + t;
        int row = c8 >> 4, ch = c8 & 15;
        *(short8*)&w2s[row * W2PAD + ch * 8] = ((const short8*)W2t)[row * 16 + ch];
    }
    __syncthreads();

    int w = t >> 6, l = t & 63;
    int lm = l & 15, lq = l >> 4;
    int base = blockIdx.x * 64 + w * 16;
    int arow = base + lm;
    int arow_c = arow < n ? arow : n - 1;
    const short8* xrow = (const short8*)(x1 + (size_t)arow_c * HID);
    short8 a0 = xrow[lq + 0], a1 = xrow[lq + 4], a2 = xrow[lq + 8], a3 = xrow[lq + 12];

    float4v acc[8];
#pragma unroll
    for (int nt = 0; nt < 8; nt++) acc[nt] = (float4v){0.f, 0.f, 0.f, 0.f};

#pragma unroll
    for (int nt = 0; nt < 8; nt++) {
        const short* bp = &w2s[(nt * 16 + lm) * W2PAD + lq * 8];
        short8 b0 = *(const short8*)(bp);
        short8 b1 = *(const short8*)(bp + 32);
        short8 b2 = *(const short8*)(bp + 64);
        short8 b3 = *(const short8*)(bp + 96);
        acc[nt] = __builtin_amdgcn_mfma_f32_16x16x32_bf16(a0, b0, acc[nt], 0, 0, 0);
        acc[nt] = __builtin_amdgcn_mfma_f32_16x16x32_bf16(a1, b1, acc[nt], 0, 0, 0);
        acc[nt] = __builtin_amdgcn_mfma_f32_16x16x32_bf16(a2, b2, acc[nt], 0, 0, 0);
        acc[nt] = __builtin_amdgcn_mfma_f32_16x16x32_bf16(a3, b3, acc[nt], 0, 0, 0);
    }

    float di[4];
    int orow[4];
#pragma unroll
    for (int r = 0; r < 4; r++) {
        orow[r] = base + lq * 4 + r;
        di[r] = dinv[orow[r] < n ? orow[r] : n - 1];
    }
#pragma unroll
    for (int nt = 0; nt < 8; nt++) {
#pragma unroll
        for (int r = 0; r < 4; r++) {
            if (orow[r] < n)
                hs2[(size_t)orow[r] * HID + nt * 16 + lm] = f2fp8(acc[nt][r] * di[r]);
        }
    }
}

// ---------------- fused gather2 (fp8 rows) + segment pooling -------------------
// one wave per 16 consecutive nodes; lane covers cols 2*lane, 2*lane+1.
__global__ void k_gp(const unsigned short* __restrict__ hs8, const int* __restrict__ eidx,
                     const int* __restrict__ off, const int* __restrict__ cnt,
                     const float* __restrict__ dinv, const float* __restrict__ b,
                     const int* __restrict__ batch, float* __restrict__ pool,
                     float* __restrict__ pcnt, int n) {
    int w = threadIdx.x >> 6;
    int lane = threadIdx.x & 63;
    int base = blockIdx.x * 64 + w * 16;
    if (base >= n) return;
    int lim = base + 16 < n ? base + 16 : n;
    float2 bb = ((const float2*)b)[lane];
    float* rp  = pool + (size_t)(blockIdx.x & (NREP - 1)) * NGRAPH * HID;
    float* rpc = pcnt + (size_t)(blockIdx.x & (NREP - 1)) * NGRAPH;

    int curg = -1;
    float r0 = 0.0f, r1 = 0.0f, runlen = 0.0f;
    for (int i = base; i < lim; i++) {
        floatx2 sf = __builtin_amdgcn_cvt_pk_f32_fp8(hs8[(size_t)i * 64 + lane], false);
        float a0 = sf.x, a1 = sf.y;         // self-loop
        int o = off[i], c = cnt[i];
        int k = 0;
        for (; k + 8 <= c; k += 8) {
            unsigned short uu[8];
#pragma unroll
            for (int j = 0; j < 8; j++)
                uu[j] = hs8[(size_t)eidx[o + k + j] * 64 + lane];
#pragma unroll
            for (int j = 0; j < 8; j++) {
                floatx2 f = __builtin_amdgcn_cvt_pk_f32_fp8(uu[j], false);
                a0 += f.x; a1 += f.y;
            }
        }
        for (; k < c; k++) {
            floatx2 f = __builtin_amdgcn_cvt_pk_f32_fp8(hs8[(size_t)eidx[o + k] * 64 + lane], false);
            a0 += f.x; a1 += f.y;
        }
        float di = dinv[i];
        float v0 = di * a0 + bb.x;
        float v1 = di * a1 + bb.y;
        int g = batch[i];
        if (g != curg) {                           // wave-uniform branch
            if (curg >= 0) {
                atomicAdd(&rp[curg * HID + 2 * lane], r0);
                atomicAdd(&rp[curg * HID + 2 * lane + 1], r1);
                if (lane == 0) atomicAdd(&rpc[curg], runlen);
            }
            curg = g; r0 = v0; r1 = v1; runlen = 1.0f;
        } else { r0 += v0; r1 += v1; runlen += 1.0f; }
    }
    if (curg >= 0) {
        atomicAdd(&rp[curg * HID + 2 * lane], r0);
        atomicAdd(&rp[curg * HID + 2 * lane + 1], r1);
        if (lane == 0) atomicAdd(&rpc[curg], runlen);
    }
}

// ---------------- replica-sum + Wlin projection + mean + log_softmax ----------
__global__ void k_lsm(const float* __restrict__ pool, const float* __restrict__ pcnt,
                      const float* __restrict__ Wlin, const float* __restrict__ blin,
                      float* __restrict__ out) {
    int w = threadIdx.x >> 6;
    int lane = threadIdx.x & 63;
    float wl[NEXP], wh[NEXP];
#pragma unroll
    for (int k = 0; k < NEXP; k++) {
        wl[k] = Wlin[(2 * lane) * NEXP + k];
        wh[k] = Wlin[(2 * lane + 1) * NEXP + k];
    }
    for (int q = 0; q < 16; q++) {
        int g = w * 16 + q;
        float s0 = 0.0f, s1 = 0.0f, cg = 0.0f;
#pragma unroll
        for (int r = 0; r < NREP; r++) {
            const float2 v = ((const float2*)(pool + (size_t)r * NGRAPH * HID + g * HID))[lane];
            s0 += v.x; s1 += v.y;
            cg += pcnt[r * NGRAPH + g];
        }
        float p[NEXP];
#pragma unroll
        for (int k = 0; k < NEXP; k++) p[k] = s0 * wl[k] + s1 * wh[k];
#pragma unroll
        for (int offd = 32; offd > 0; offd >>= 1) {
#pragma unroll
            for (int k = 0; k < NEXP; k++) p[k] += __shfl_down(p[k], offd, 64);
        }
        if (lane == 0) {
            float inv = 1.0f / fmaxf(cg, 1.0f);
            float v[NEXP], m = -1e30f;
#pragma unroll
            for (int k = 0; k < NEXP; k++) {
                v[k] = p[k] * inv + blin[k];
                m = fmaxf(m, v[k]);
            }
            float s = 0.0f;
#pragma unroll
            for (int k = 0; k < NEXP; k++) s += expf(v[k] - m);
            float ls = logf(s);
#pragma unroll
            for (int k = 0; k < NEXP; k++) out[g * NEXP + k] = v[k] - m - ls;
        }
    }
}

extern "C" void kernel_launch(void* const* d_in, const int* in_sizes, int n_in,
                              void* d_out, int out_size, void* d_ws, size_t ws_size,
                              hipStream_t stream) {
    const float* an   = (const float*)d_in[0];
    const float* pos  = (const float*)d_in[1];
    const int*   ei   = (const int*)d_in[2];     // [2, E] flat (int32 view)
    const int*   batch= (const int*)d_in[3];
    const float* W1   = (const float*)d_in[4];
    const float* b1   = (const float*)d_in[5];
    const float* W2   = (const float*)d_in[6];
    const float* b2   = (const float*)d_in[7];
    const float* Wlin = (const float*)d_in[8];
    const float* blin = (const float*)d_in[9];
    float* out = (float*)d_out;

    const int n = in_sizes[0];
    const int e = in_sizes[2] / 2;
    const int* src = ei;
    const int* dst = ei + e;

    const int nbuck = (n + 255) >> 8;            // coarse buckets (<= MAXB)
    const int ch    = (e + EPC - 1) / EPC;       // chunks

    // workspace layout (16B-aligned buffers first)
    char* p = (char*)d_ws;
    unsigned short* bufX = (unsigned short*)p;  p += sizeof(short) * (size_t)n * HID; // x1 bf16
    unsigned char*  f8   = (unsigned char*)p;   p += (size_t)n * HID;                 // hs2 fp8
    float4* xs    = (float4*)p;       p += sizeof(float4) * (size_t)n;
    float4* agg4  = (float4*)p;       p += sizeof(float4) * (size_t)n;
    unsigned short* W2t  = (unsigned short*)p;  p += sizeof(short) * HID * HID;
    float* dinv   = (float*)p;        p += sizeof(float) * (size_t)n;
    float* pool   = (float*)p;        p += sizeof(float) * NREP * NGRAPH * HID;
    float* pcnt   = (float*)p;        p += sizeof(float) * NREP * NGRAPH;
    int*   cnt    = (int*)p;          p += sizeof(int) * (size_t)n;
    int*   off    = (int*)p;          p += sizeof(int) * (size_t)n;
    int*   boff   = (int*)p;          p += sizeof(int) * (MAXB + 1);
    int*   runcnt = (int*)p;          p += sizeof(int) * (size_t)ch * nbuck;
    unsigned* binned = (unsigned*)p;  p += sizeof(unsigned) * (size_t)e;
    int*   eidx   = (int*)p;          p += sizeof(int) * (size_t)e;

    // CSR build via two-phase counting sort
    k_init0<<<(NREP * NGRAPH * HID + 255) / 256, 256, 0, stream>>>(pool, pcnt, W2, W2t);
    k_hist<<<ch, 256, 0, stream>>>(dst, runcnt, e, nbuck);
    k_scan2<<<1, 512, 0, stream>>>(runcnt, boff, e, ch, nbuck);
    k_binA<<<ch, 256, 0, stream>>>(src, dst, runcnt, binned, e, nbuck);
    k_binB<<<nbuck, 256, 0, stream>>>(binned, boff, an, pos, cnt, off, dinv, xs, eidx, n);

    // layer 1 (4-dim gather, then dense)
    k_gx<<<(n + 255) / 256, 256, 0, stream>>>(xs, eidx, off, cnt, agg4, n);
    k_h1<<<(n + 3) / 4, 256, 0, stream>>>(agg4, W1, b1, dinv, (unsigned*)bufX, n);

    // layer 2 (MFMA, fp8 out)
    k_h2<<<(n + 63) / 64, 256, 0, stream>>>(bufX, W2t, dinv, f8, n);

    // fused gather2 (fp8) + pooling, then projection + log_softmax
    k_gp<<<(n + 63) / 64, 256, 0, stream>>>((const unsigned short*)f8, eidx, off, cnt,
                                            dinv, b2, batch, pool, pcnt, n);
    k_lsm<<<1, 256, 0, stream>>>(pool, pcnt, Wlin, blin, out);
}

// Round 7
// 310.453 us; speedup vs baseline: 11.8827x; 1.0630x over previous
//
#include <hip/hip_runtime.h>
#include <math.h>

#define HID 128
#define NEXP 8
#define NGRAPH 64
#define EPC 16384      // edges per chunk (pass A blocks)
#define MAXB 512       // max coarse buckets (n <= 131072)
#define NREP 8         // pool replicas (atomic-contention spreading)
#define NPS 4          // nodes per slot in k_gz

__device__ inline unsigned short f2bf(float f) {
    unsigned u = __float_as_uint(f);
    u += 0x7FFF + ((u >> 16) & 1);          // RNE
    return (unsigned short)(u >> 16);
}
__device__ inline unsigned packbf(float lo, float hi) {
    return (unsigned)f2bf(lo) | ((unsigned)f2bf(hi) << 16);
}
__device__ inline float bf2f(unsigned short u) {
    return __uint_as_float(((unsigned)u) << 16);
}

// ---------------- init: pool/pcnt zero, C = W2@Wlin, bb2 = b2@Wlin -------------
__global__ void k_init0(float* __restrict__ pool, float* __restrict__ pcnt,
                        const float* __restrict__ W2, const float* __restrict__ Wlin,
                        const float* __restrict__ b2, float* __restrict__ C,
                        float* __restrict__ bb2) {
    int i = blockIdx.x * 256 + threadIdx.x;
    if (i < NREP * NGRAPH * NEXP) pool[i] = 0.0f;
    if (i < NREP * NGRAPH) pcnt[i] = 0.0f;
    int ci = i - NREP * NGRAPH * NEXP;
    if (ci >= 0 && ci < HID * NEXP) {        // C[k][j] = sum_m W2[k][m]*Wlin[m][j]
        int k = ci >> 3, j = ci & 7;
        float s = 0.0f;
        for (int m = 0; m < HID; m++) s += W2[k * HID + m] * Wlin[m * NEXP + j];
        C[ci] = s;
    }
    int bi = ci - HID * NEXP;
    if (bi >= 0 && bi < NEXP) {              // bb2[j] = sum_m b2[m]*Wlin[m][j]
        float s = 0.0f;
        for (int m = 0; m < HID; m++) s += b2[m] * Wlin[m * NEXP + bi];
        bb2[bi] = s;
    }
}

// ---------------- pass 0: per-chunk LDS histogram over coarse buckets ---------
// runcnt layout: [b][ch] so the scan streams contiguously.
__global__ void k_hist(const int* __restrict__ dst, int* __restrict__ runcnt,
                       int e, int ch, int nbuck) {
    __shared__ int h[MAXB];
    int c = blockIdx.x, t = threadIdx.x;
    for (int b = t; b < nbuck; b += 256) h[b] = 0;
    __syncthreads();
    int start = c * EPC;
    int end = start + EPC < e ? start + EPC : e;
    for (int i = start + t; i < end; i += 256)
        atomicAdd(&h[dst[i] >> 8], 1);
    __syncthreads();
    for (int b = t; b < nbuck; b += 256)
        runcnt[b * ch + c] = h[b];
}

// ---------------- scan2: bucket totals + boff scan + runcnt -> global offsets --
__global__ void k_scan2(int* __restrict__ runcnt, int* __restrict__ boff,
                        int e, int ch, int nbuck) {
    __shared__ int s[512];
    int t = threadIdx.x;
    int tot = 0;
    if (t < nbuck)
        for (int c = 0; c < ch; c++) tot += runcnt[t * ch + c];
    s[t] = tot;
    __syncthreads();
    for (int d = 1; d < 512; d <<= 1) {
        int x = (t >= d) ? s[t - d] : 0;
        __syncthreads();
        s[t] += x;
        __syncthreads();
    }
    if (t < nbuck) {
        int run = s[t] - tot;               // exclusive
        boff[t] = run;
        for (int c = 0; c < ch; c++) {
            int v = runcnt[t * ch + c];
            runcnt[t * ch + c] = run;
            run += v;
        }
    }
    if (t == 0) boff[nbuck] = e;
}

// ---------------- pass A: bin edges into bucket-contiguous order --------------
__global__ void k_binA(const int* __restrict__ src, const int* __restrict__ dst,
                       const int* __restrict__ runcnt, unsigned* __restrict__ binned,
                       int e, int ch, int nbuck) {
    __shared__ int cur[MAXB];
    int c = blockIdx.x, t = threadIdx.x;
    for (int b = t; b < nbuck; b += 256) cur[b] = runcnt[b * ch + c];
    __syncthreads();
    int start = c * EPC;
    int end = start + EPC < e ? start + EPC : e;
    for (int i = start + t; i < end; i += 256) {
        int d = dst[i];
        int p = atomicAdd(&cur[d >> 8], 1);
        binned[p] = ((unsigned)(d & 255) << 24) | (unsigned)src[i];
    }
}

// ---------------- pass B: per-bucket fine sort + cnt/off/dinv + xs -------------
__global__ void k_binB(const unsigned* __restrict__ binned, const int* __restrict__ boff,
                       const float* __restrict__ an, const float* __restrict__ pos,
                       int* __restrict__ cnt, int* __restrict__ off,
                       float* __restrict__ dinv, float4* __restrict__ xs,
                       int* __restrict__ eidx, int n) {
    __shared__ int h[256];
    __shared__ int sc[256];
    __shared__ int cur[256];
    int b = blockIdx.x, t = threadIdx.x;
    int s0 = boff[b], s1 = boff[b + 1];
    h[t] = 0;
    __syncthreads();
    for (int k = s0 + t; k < s1; k += 256)
        atomicAdd(&h[binned[k] >> 24], 1);
    __syncthreads();
    int v = h[t];
    sc[t] = v;
    __syncthreads();
    for (int d = 1; d < 256; d <<= 1) {
        int x = (t >= d) ? sc[t - d] : 0;
        __syncthreads();
        sc[t] += x;
        __syncthreads();
    }
    int ex = sc[t] - v;          // exclusive within bucket
    cur[t] = ex;
    int node = (b << 8) + t;
    if (node < n) {
        float di = rsqrtf((float)v + 1.0f);   // +1 = self-loop
        cnt[node]  = v;
        off[node]  = s0 + ex;
        dinv[node] = di;
        xs[node] = make_float4(an[node] * di, pos[3 * node] * di,
                               pos[3 * node + 1] * di, pos[3 * node + 2] * di);
    }
    __syncthreads();
    for (int k = s0 + t; k < s1; k += 256) {
        unsigned u = binned[k];
        int p = atomicAdd(&cur[u >> 24], 1);
        eidx[s0 + p] = (int)(u & 0xFFFFFF);
    }
}

// ---------------- layer-1 gather in 4-dim space: agg4 = xs[i] + sum xs[src] ----
__global__ void k_gx(const float4* __restrict__ xs, const int* __restrict__ eidx,
                     const int* __restrict__ off, const int* __restrict__ cnt,
                     float4* __restrict__ agg4, int n) {
    int i = blockIdx.x * 256 + threadIdx.x;
    if (i >= n) return;
    float4 a = xs[i];                       // self-loop
    int o = off[i], c = cnt[i];
    int k = 0;
    for (; k + 8 <= c; k += 8) {
        int id[8];
#pragma unroll
        for (int j = 0; j < 8; j++) id[j] = eidx[o + k + j];
        float4 vv[8];
#pragma unroll
        for (int j = 0; j < 8; j++) vv[j] = xs[id[j]];
#pragma unroll
        for (int j = 0; j < 8; j++) {
            a.x += vv[j].x; a.y += vv[j].y; a.z += vv[j].z; a.w += vv[j].w;
        }
    }
    for (; k < c; k++) {
        float4 vv = xs[eidx[o + k]];
        a.x += vv.x; a.y += vv.y; a.z += vv.z; a.w += vv.w;
    }
    agg4[i] = a;
}

// ---------------- fused layer-1 dense + z projection ---------------------------
// x1_i = relu(dinv*(agg4@W1)+b1) in wave registers; z_i = (x1_i@C)*dinv, bf16[8]
__global__ void k_hz(const float4* __restrict__ agg4, const float* __restrict__ W1,
                     const float* __restrict__ b1, const float* __restrict__ C,
                     const float* __restrict__ dinv, unsigned short* __restrict__ z,
                     int n) {
    __shared__ float xh[4][HID];
    int w = threadIdx.x >> 6;
    int i = blockIdx.x * 4 + w;
    int p = threadIdx.x & 63;
    int ic = i < n ? i : n - 1;
    const float2* W1v = (const float2*)W1;
    float2 w0 = W1v[0 * 64 + p], w1 = W1v[1 * 64 + p],
           w2 = W1v[2 * 64 + p], w3 = W1v[3 * 64 + p];
    float4 a = agg4[ic];
    float di = dinv[ic];
    float2 bb = ((const float2*)b1)[p];
    float h0 = fmaxf(di * (a.x * w0.x + a.y * w1.x + a.z * w2.x + a.w * w3.x) + bb.x, 0.0f);
    float h1 = fmaxf(di * (a.x * w0.y + a.y * w1.y + a.z * w2.y + a.w * w3.y) + bb.y, 0.0f);
    xh[w][2 * p]     = h0;
    xh[w][2 * p + 1] = h1;
    __syncthreads();
    // lane p: seg = p>>3 covers cols seg*16..+15, comp j = p&7
    int seg = p >> 3, j = p & 7;
    float val = 0.0f;
#pragma unroll
    for (int q = 0; q < 16; q++) {
        int c = seg * 16 + q;
        val += xh[w][c] * C[c * NEXP + j];
    }
#pragma unroll
    for (int m = 8; m < 64; m <<= 1)
        val += __shfl_xor(val, m, 64);
    if (p < 8 && i < n) z[(size_t)i * NEXP + p] = f2bf(val * di);
}

// ---------------- fused gather2 (8-dim bf16 z) + segment pooling ---------------
// wave = 8 slots x 8 comp-lanes; slot handles NPS consecutive nodes; register
// run-accumulation by graph; flush to replicated pool via atomics.
__global__ void k_gz(const unsigned short* __restrict__ z, const int* __restrict__ eidx,
                     const int* __restrict__ off, const int* __restrict__ cnt,
                     const float* __restrict__ dinv, const int* __restrict__ batch,
                     float* __restrict__ pool, float* __restrict__ pcnt, int n) {
    int t = threadIdx.x;
    int slot = t >> 3;          // 0..31 within block
    int j = t & 7;
    int i0 = blockIdx.x * (32 * NPS) + slot * NPS;
    if (i0 >= n) return;
    int i1 = i0 + NPS < n ? i0 + NPS : n;
    int rep = (blockIdx.x + slot) & (NREP - 1);
    float* rp  = pool + (size_t)rep * NGRAPH * NEXP;
    float* rpc = pcnt + (size_t)rep * NGRAPH;

    int curg = -1;
    float r = 0.0f, runlen = 0.0f;
    for (int i = i0; i < i1; i++) {
        float acc = bf2f(z[(size_t)i * NEXP + j]);   // self-loop
        int o = off[i], c = cnt[i];
        int k = 0;
        for (; k + 4 <= c; k += 4) {
            int s0 = eidx[o + k], s1 = eidx[o + k + 1];
            int s2 = eidx[o + k + 2], s3 = eidx[o + k + 3];
            unsigned short u0 = z[(size_t)s0 * NEXP + j];
            unsigned short u1 = z[(size_t)s1 * NEXP + j];
            unsigned short u2 = z[(size_t)s2 * NEXP + j];
            unsigned short u3 = z[(size_t)s3 * NEXP + j];
            acc += bf2f(u0) + bf2f(u1) + bf2f(u2) + bf2f(u3);
        }
        for (; k < c; k++)
            acc += bf2f(z[(size_t)eidx[o + k] * NEXP + j]);
        float v = dinv[i] * acc;
        int g = batch[i];
        if (g != curg) {                     // slot-uniform branch
            if (curg >= 0) {
                atomicAdd(&rp[curg * NEXP + j], r);
                if (j == 0) atomicAdd(&rpc[curg], runlen);
            }
            curg = g; r = v; runlen = 1.0f;
        } else { r += v; runlen += 1.0f; }
    }
    if (curg >= 0) {
        atomicAdd(&rp[curg * NEXP + j], r);
        if (j == 0) atomicAdd(&rpc[curg], runlen);
    }
}

// ---------------- replica-sum + mean + (blin + b2@Wlin) + log_softmax ----------
__global__ void k_lsm(const float* __restrict__ pool, const float* __restrict__ pcnt,
                      const float* __restrict__ blin, const float* __restrict__ bb2,
                      float* __restrict__ out) {
    int g = threadIdx.x;
    if (g >= NGRAPH) return;
    float p[NEXP];
#pragma unroll
    for (int k = 0; k < NEXP; k++) p[k] = 0.0f;
    float cg = 0.0f;
#pragma unroll
    for (int rr = 0; rr < NREP; rr++) {
#pragma unroll
        for (int k = 0; k < NEXP; k++) p[k] += pool[rr * NGRAPH * NEXP + g * NEXP + k];
        cg += pcnt[rr * NGRAPH + g];
    }
    float inv = 1.0f / fmaxf(cg, 1.0f);
    float v[NEXP], m = -1e30f;
#pragma unroll
    for (int k = 0; k < NEXP; k++) {
        v[k] = p[k] * inv + blin[k] + bb2[k];
        m = fmaxf(m, v[k]);
    }
    float s = 0.0f;
#pragma unroll
    for (int k = 0; k < NEXP; k++) s += expf(v[k] - m);
    float ls = logf(s);
#pragma unroll
    for (int k = 0; k < NEXP; k++) out[g * NEXP + k] = v[k] - m - ls;
}

extern "C" void kernel_launch(void* const* d_in, const int* in_sizes, int n_in,
                              void* d_out, int out_size, void* d_ws, size_t ws_size,
                              hipStream_t stream) {
    const float* an   = (const float*)d_in[0];
    const float* pos  = (const float*)d_in[1];
    const int*   ei   = (const int*)d_in[2];     // [2, E] flat (int32 view)
    const int*   batch= (const int*)d_in[3];
    const float* W1   = (const float*)d_in[4];
    const float* b1   = (const float*)d_in[5];
    const float* W2   = (const float*)d_in[6];
    const float* b2   = (const float*)d_in[7];
    const float* Wlin = (const float*)d_in[8];
    const float* blin = (const float*)d_in[9];
    float* out = (float*)d_out;

    const int n = in_sizes[0];
    const int e = in_sizes[2] / 2;
    const int* src = ei;
    const int* dst = ei + e;

    const int nbuck = (n + 255) >> 8;            // coarse buckets (<= MAXB)
    const int ch    = (e + EPC - 1) / EPC;       // chunks

    // workspace layout (16B-aligned buffers first)
    char* p = (char*)d_ws;
    float4* xs    = (float4*)p;       p += sizeof(float4) * (size_t)n;
    float4* agg4  = (float4*)p;       p += sizeof(float4) * (size_t)n;
    unsigned short* z = (unsigned short*)p;  p += sizeof(short) * (size_t)n * NEXP;
    float* C      = (float*)p;        p += sizeof(float) * HID * NEXP;
    float* bb2    = (float*)p;        p += sizeof(float) * NEXP;
    float* dinv   = (float*)p;        p += sizeof(float) * (size_t)n;
    float* pool   = (float*)p;        p += sizeof(float) * NREP * NGRAPH * NEXP;
    float* pcnt   = (float*)p;        p += sizeof(float) * NREP * NGRAPH;
    int*   cnt    = (int*)p;          p += sizeof(int) * (size_t)n;
    int*   off    = (int*)p;          p += sizeof(int) * (size_t)n;
    int*   boff   = (int*)p;          p += sizeof(int) * (MAXB + 1);
    int*   runcnt = (int*)p;          p += sizeof(int) * (size_t)ch * nbuck;
    unsigned* binned = (unsigned*)p;  p += sizeof(unsigned) * (size_t)e;
    int*   eidx   = (int*)p;          p += sizeof(int) * (size_t)e;

    // init + CSR build via two-phase counting sort
    const int initN = NREP * NGRAPH * NEXP + HID * NEXP + NEXP;
    k_init0<<<(initN + 255) / 256, 256, 0, stream>>>(pool, pcnt, W2, Wlin, b2, C, bb2);
    k_hist<<<ch, 256, 0, stream>>>(dst, runcnt, e, ch, nbuck);
    k_scan2<<<1, 512, 0, stream>>>(runcnt, boff, e, ch, nbuck);
    k_binA<<<ch, 256, 0, stream>>>(src, dst, runcnt, binned, e, ch, nbuck);
    k_binB<<<nbuck, 256, 0, stream>>>(binned, boff, an, pos, cnt, off, dinv, xs, eidx, n);

    // layer 1 gather (4-dim) + fused dense/projection to z (8-dim)
    k_gx<<<(n + 255) / 256, 256, 0, stream>>>(xs, eidx, off, cnt, agg4, n);
    k_hz<<<(n + 3) / 4, 256, 0, stream>>>(agg4, W1, b1, C, dinv, z, n);

    // layer 2 gather in 8-dim z-space + pooling, then log_softmax
    k_gz<<<(n + 32 * NPS - 1) / (32 * NPS), 256, 0, stream>>>(z, eidx, off, cnt,
                                                              dinv, batch, pool, pcnt, n);
    k_lsm<<<1, 64, 0, stream>>>(pool, pcnt, blin, bb2, out);
}